// Round 1
// baseline (3257.093 us; speedup 1.0000x reference)
//
#include <hip/hip_runtime.h>
#include <math.h>

// ---------------------------------------------------------------------------
// DAHead: B=8, Cin=512, Ci=128, H=W=64, N=4096, Ck=16, NC=19.  All fp32.
// Buffers in ws:  bufA @0 (16MB), bufD @S (16MB), bufB @2S (16MB),
//                 qb @3S (2MB), kb @3S+2MB (2MB), egy @3S+4MB (0.5MB)
// ---------------------------------------------------------------------------

// ---- 3x3 conv (SAME) + folded-BN + ReLU.  Cout=128 fixed, Cin param. ------
// grid (16 spatial tiles [4x4 of 16x16], 4 co-tiles of 32, 8 batch), 256 thr.
__global__ __launch_bounds__(256) void conv3x3_bnrelu(
    const float* __restrict__ x, const float* __restrict__ w,
    const float* __restrict__ bn, float* __restrict__ out, int Cin)
{
    const int t   = threadIdx.x;
    const int ts  = blockIdx.x;
    const int ty0 = (ts >> 2) << 4;
    const int tx0 = (ts & 3) << 4;
    const int co0 = blockIdx.y << 5;
    const int b   = blockIdx.z;

    const int q   = t & 63;
    const int qy  = q >> 3;      // 0..7 -> rows 2qy,2qy+1
    const int qx  = q & 7;       // 0..7 -> cols qx, qx+8
    const int cog = t >> 6;      // 0..3 -> 8 co each

    __shared__ float ilds[8 * 18 * 19];   // [cin8][row18][col stride19]
    __shared__ float wlds[8 * 9 * 32];    // [cin8][tap9][co32]

    float acc[2][2][8];
#pragma unroll
    for (int a0 = 0; a0 < 2; a0++)
#pragma unroll
        for (int a1 = 0; a1 < 2; a1++)
#pragma unroll
            for (int a2 = 0; a2 < 8; a2++) acc[a0][a1][a2] = 0.f;

    const int nchunks = Cin >> 3;
    for (int ch = 0; ch < nchunks; ++ch) {
        const int cin0 = ch << 3;
        for (int idx = t; idx < 8 * 18 * 18; idx += 256) {
            int cl  = idx / 324;
            int rem = idx - cl * 324;
            int r   = rem / 18;
            int c   = rem - r * 18;
            int gy  = ty0 + r - 1;
            int gx  = tx0 + c - 1;
            float v = 0.f;
            if ((unsigned)gy < 64u && (unsigned)gx < 64u)
                v = x[(((size_t)b * Cin + (cin0 + cl)) << 12) + (gy << 6) + gx];
            ilds[cl * 342 + r * 19 + c] = v;
        }
        for (int idx = t; idx < 8 * 9 * 32; idx += 256) {
            int col  = idx & 31;
            int rest = idx >> 5;      // cl*9 + kk
            int cl   = rest / 9;
            int kk   = rest - cl * 9;
            wlds[idx] = w[((size_t)(co0 + col) * Cin + cin0 + cl) * 9 + kk];
        }
        __syncthreads();

#pragma unroll 1
        for (int cl = 0; cl < 8; ++cl) {
            const float* ib = &ilds[cl * 342];
            const float* wb = &wlds[cl * 288];
#pragma unroll
            for (int ky = 0; ky < 3; ++ky) {
                const int r0 = 2 * qy + ky;
#pragma unroll
                for (int kx = 0; kx < 3; ++kx) {
                    float wv[8];
#pragma unroll
                    for (int ci = 0; ci < 8; ci++)
                        wv[ci] = wb[(ky * 3 + kx) * 32 + (cog << 3) + ci];
                    float i00 = ib[r0 * 19 + qx + kx];
                    float i01 = ib[r0 * 19 + qx + 8 + kx];
                    float i10 = ib[r0 * 19 + 19 + qx + kx];
                    float i11 = ib[r0 * 19 + 19 + qx + 8 + kx];
#pragma unroll
                    for (int ci = 0; ci < 8; ci++) {
                        acc[0][0][ci] = fmaf(i00, wv[ci], acc[0][0][ci]);
                        acc[0][1][ci] = fmaf(i01, wv[ci], acc[0][1][ci]);
                        acc[1][0][ci] = fmaf(i10, wv[ci], acc[1][0][ci]);
                        acc[1][1][ci] = fmaf(i11, wv[ci], acc[1][1][ci]);
                    }
                }
            }
        }
        __syncthreads();
    }

#pragma unroll
    for (int ci = 0; ci < 8; ci++) {
        int co = co0 + (cog << 3) + ci;
        float sc = bn[co], sh = bn[128 + co];
#pragma unroll
        for (int dy = 0; dy < 2; dy++) {
            int y = ty0 + 2 * qy + dy;
#pragma unroll
            for (int dx = 0; dx < 2; dx++) {
                int xx = tx0 + qx + 8 * dx;
                float v = fmaf(acc[dy][dx][ci], sc, sh);
                v = v > 0.f ? v : 0.f;
                out[(((size_t)b * 128 + co) << 12) + (y << 6) + xx] = v;
            }
        }
    }
}

// ---- PAM 1x1: b_ = Wb*A + bb, c_ = Wc*A + bc.  grid (16 n-tiles, 8 b) -----
__global__ __launch_bounds__(256) void pam_bc_1x1(
    const float* __restrict__ A, const float* __restrict__ Wb, const float* __restrict__ bb,
    const float* __restrict__ Wc, const float* __restrict__ bc,
    float* __restrict__ bo, float* __restrict__ co)
{
    __shared__ float wl[2 * 16 * 128];
    __shared__ float bl[32];
    const int t = threadIdx.x;
    const int n = (blockIdx.x << 8) + t;
    const int b = blockIdx.y;
    for (int idx = t; idx < 2048; idx += 256) { wl[idx] = Wb[idx]; wl[2048 + idx] = Wc[idx]; }
    if (t < 16) { bl[t] = bb[t]; bl[16 + t] = bc[t]; }
    __syncthreads();
    float ab[16], ac[16];
#pragma unroll
    for (int k = 0; k < 16; k++) { ab[k] = 0.f; ac[k] = 0.f; }
    for (int chn = 0; chn < 128; ++chn) {
        float a = A[(((size_t)b * 128 + chn) << 12) + n];
#pragma unroll
        for (int k = 0; k < 16; k++) {
            ab[k] = fmaf(wl[k * 128 + chn], a, ab[k]);
            ac[k] = fmaf(wl[2048 + k * 128 + chn], a, ac[k]);
        }
    }
#pragma unroll
    for (int k = 0; k < 16; k++) {
        bo[(((size_t)b * 16 + k) << 12) + n] = ab[k] + bl[k];
        co[(((size_t)b * 16 + k) << 12) + n] = ac[k] + bl[16 + k];
    }
}

// ---- PAM 1x1: d_ = Wd*A + bd.  grid (16 n-tiles, 4 co-tiles, 8 b) ---------
__global__ __launch_bounds__(256) void pam_d_1x1(
    const float* __restrict__ A, const float* __restrict__ Wd, const float* __restrict__ bd,
    float* __restrict__ dout)
{
    __shared__ float wl[32 * 128];
    __shared__ float bl[32];
    const int t   = threadIdx.x;
    const int n   = (blockIdx.x << 8) + t;
    const int co0 = blockIdx.y << 5;
    const int b   = blockIdx.z;
    for (int idx = t; idx < 4096; idx += 256) {
        int c2 = idx >> 7, chv = idx & 127;
        wl[idx] = Wd[(co0 + c2) * 128 + chv];
    }
    if (t < 32) bl[t] = bd[co0 + t];
    __syncthreads();
    float acc[32];
#pragma unroll
    for (int k = 0; k < 32; k++) acc[k] = 0.f;
    for (int chn = 0; chn < 128; ++chn) {
        float a = A[(((size_t)b * 128 + chn) << 12) + n];
#pragma unroll
        for (int k = 0; k < 32; k++) acc[k] = fmaf(wl[k * 128 + chn], a, acc[k]);
    }
#pragma unroll
    for (int k = 0; k < 32; k++)
        dout[(((size_t)b * 128 + co0 + k) << 12) + n] = acc[k] + bl[k];
}

// ---- PAM flash attention. Q=b_[16,N] K=c_[16,N] V=d_[128,N].
//  feat[c,n] = sum_m softmax_m(Q.n dot K.m) V[c,m];  Y = alpha*feat + Y (in place)
//  grid (128 q-tiles of 32, 8 b), 256 thr.
__global__ __launch_bounds__(256) void pam_attn(
    const float* __restrict__ bq, const float* __restrict__ ck,
    const float* __restrict__ dv, const float* __restrict__ alpha,
    float* __restrict__ Y)
{
    const int t  = threadIdx.x;
    const int b  = blockIdx.y;
    const int n0 = blockIdx.x << 5;

    __shared__ float Ql[32 * 17];
    __shared__ float Kl[16 * 64];
    __shared__ float Vl[128 * 66];
    __shared__ float Sl[32 * 66];
    __shared__ float pm[32 * 9];
    __shared__ float mrun[32], lrun[32], fac[32];

    for (int idx = t; idx < 512; idx += 256) {
        int qq = idx >> 4, k = idx & 15;
        Ql[qq * 17 + k] = bq[(((size_t)b * 16 + k) << 12) + n0 + qq];
    }
    if (t < 32) { mrun[t] = -INFINITY; lrun[t] = 0.f; }
    __syncthreads();

    float O[16];
#pragma unroll
    for (int i = 0; i < 16; i++) O[i] = 0.f;

    const int sq   = t & 31;
    const int mseg = t >> 5;
    const int qg   = t & 7;
    const int cg   = t >> 3;

    for (int m0 = 0; m0 < 4096; m0 += 64) {
        for (int idx = t; idx < 1024; idx += 256) {
            int k = idx >> 6, m = idx & 63;
            Kl[k * 64 + m] = ck[(((size_t)b * 16 + k) << 12) + m0 + m];
        }
        for (int idx = t; idx < 8192; idx += 256) {
            int c = idx >> 6, m = idx & 63;
            Vl[c * 66 + m] = dv[(((size_t)b * 128 + c) << 12) + m0 + m];
        }
        __syncthreads();
        // S = Q K^T (each thread: row sq, 8 cols)
#pragma unroll
        for (int j = 0; j < 8; ++j) {
            int m = (mseg << 3) + j;
            float s = 0.f;
#pragma unroll
            for (int k = 0; k < 16; k++) s = fmaf(Ql[sq * 17 + k], Kl[k * 64 + m], s);
            Sl[sq * 66 + m] = s;
        }
        __syncthreads();
        {
            float pmax = -INFINITY;
#pragma unroll
            for (int j = 0; j < 8; j++) pmax = fmaxf(pmax, Sl[sq * 66 + (mseg << 3) + j]);
            pm[sq * 9 + mseg] = pmax;
        }
        __syncthreads();
        if (t < 32) {
            float rm = pm[t * 9];
#pragma unroll
            for (int j = 1; j < 8; j++) rm = fmaxf(rm, pm[t * 9 + j]);
            float nm = fmaxf(mrun[t], rm);
            fac[t]   = __expf(mrun[t] - nm);
            mrun[t]  = nm;
        }
        __syncthreads();
        {
            float mv = mrun[sq];
            float ps = 0.f;
#pragma unroll
            for (int j = 0; j < 8; j++) {
                int m = (mseg << 3) + j;
                float p = __expf(Sl[sq * 66 + m] - mv);
                Sl[sq * 66 + m] = p;
                ps += p;
            }
            pm[sq * 9 + mseg] = ps;
        }
        __syncthreads();
        if (t < 32) {
            float rs = 0.f;
#pragma unroll
            for (int j = 0; j < 8; j++) rs += pm[t * 9 + j];
            lrun[t] = lrun[t] * fac[t] + rs;
        }
        // PV (runs concurrently with the lrun update above; no shared hazard)
        {
            float f0 = fac[qg * 4 + 0], f1 = fac[qg * 4 + 1];
            float f2 = fac[qg * 4 + 2], f3 = fac[qg * 4 + 3];
#pragma unroll
            for (int ci = 0; ci < 4; ci++) {
                O[0 + ci] *= f0; O[4 + ci] *= f1; O[8 + ci] *= f2; O[12 + ci] *= f3;
            }
#pragma unroll 4
            for (int m = 0; m < 64; ++m) {
                float p0 = Sl[(qg * 4 + 0) * 66 + m];
                float p1 = Sl[(qg * 4 + 1) * 66 + m];
                float p2 = Sl[(qg * 4 + 2) * 66 + m];
                float p3 = Sl[(qg * 4 + 3) * 66 + m];
#pragma unroll
                for (int ci = 0; ci < 4; ci++) {
                    float v = Vl[(cg * 4 + ci) * 66 + m];
                    O[0 + ci]  = fmaf(p0, v, O[0 + ci]);
                    O[4 + ci]  = fmaf(p1, v, O[4 + ci]);
                    O[8 + ci]  = fmaf(p2, v, O[8 + ci]);
                    O[12 + ci] = fmaf(p3, v, O[12 + ci]);
                }
            }
        }
        __syncthreads();
    }

    float al = alpha[0];
#pragma unroll
    for (int qi = 0; qi < 4; qi++) {
        int qq = qg * 4 + qi;
        float inv = 1.f / lrun[qq];
        int n = n0 + qq;
#pragma unroll
        for (int ci = 0; ci < 4; ci++) {
            int c = cg * 4 + ci;
            size_t idx = (((size_t)b * 128 + c) << 12) + n;
            Y[idx] = fmaf(al, O[qi * 4 + ci] * inv, Y[idx]);
        }
    }
}

// ---- CAM gram: egy[b,i,j] = dot(B[b,i,:], B[b,j,:]).  grid (16 tiles, 8 b) -
__global__ __launch_bounds__(256) void cam_energy(
    const float* __restrict__ Bf, float* __restrict__ egy)
{
    const int t  = threadIdx.x;
    const int b  = blockIdx.y;
    const int i0 = (blockIdx.x >> 2) << 5;
    const int j0 = (blockIdx.x & 3) << 5;
    __shared__ float Bi[32 * 65], Bj[32 * 65];
    const int ig = t >> 4, jg = t & 15;
    float a00 = 0.f, a01 = 0.f, a10 = 0.f, a11 = 0.f;
    for (int nc = 0; nc < 4096; nc += 64) {
        for (int idx = t; idx < 2048; idx += 256) {
            int r = idx >> 6, n = idx & 63;
            Bi[r * 65 + n] = Bf[(((size_t)b * 128 + i0 + r) << 12) + nc + n];
            Bj[r * 65 + n] = Bf[(((size_t)b * 128 + j0 + r) << 12) + nc + n];
        }
        __syncthreads();
        for (int n = 0; n < 64; ++n) {
            float bi0 = Bi[(ig * 2 + 0) * 65 + n], bi1 = Bi[(ig * 2 + 1) * 65 + n];
            float bj0 = Bj[(jg * 2 + 0) * 65 + n], bj1 = Bj[(jg * 2 + 1) * 65 + n];
            a00 = fmaf(bi0, bj0, a00);
            a01 = fmaf(bi0, bj1, a01);
            a10 = fmaf(bi1, bj0, a10);
            a11 = fmaf(bi1, bj1, a11);
        }
        __syncthreads();
    }
    size_t base = (size_t)b * 16384;
    egy[base + (i0 + ig * 2 + 0) * 128 + (j0 + jg * 2 + 0)] = a00;
    egy[base + (i0 + ig * 2 + 0) * 128 + (j0 + jg * 2 + 1)] = a01;
    egy[base + (i0 + ig * 2 + 1) * 128 + (j0 + jg * 2 + 0)] = a10;
    egy[base + (i0 + ig * 2 + 1) * 128 + (j0 + jg * 2 + 1)] = a11;
}

// ---- CAM softmax of (rowmax - e) over last axis, in place. grid(8) x 128 --
__global__ __launch_bounds__(128) void cam_softmax(float* __restrict__ egy)
{
    const int b = blockIdx.x;
    const int i = threadIdx.x;
    float* row = egy + (size_t)b * 16384 + i * 128;
    float mn = INFINITY;
    for (int j = 0; j < 128; j++) mn = fminf(mn, row[j]);
    // softmax(max-e): stabilized p_j = exp(mn - e_j)
    float s = 0.f;
    for (int j = 0; j < 128; j++) { float p = __expf(mn - row[j]); row[j] = p; s += p; }
    float inv = 1.f / s;
    for (int j = 0; j < 128; j++) row[j] *= inv;
}

// ---- CAM feat: out[b,c,n] = beta * sum_d attn[c,d] B[b,d,n] + B[b,c,n] ----
// grid (16 n-tiles, 4 c-tiles, 8 b)
__global__ __launch_bounds__(256) void cam_feat(
    const float* __restrict__ attn, const float* __restrict__ Bf,
    const float* __restrict__ beta, float* __restrict__ outb)
{
    const int t  = threadIdx.x;
    const int n  = (blockIdx.x << 8) + t;
    const int c0 = blockIdx.y << 5;
    const int b  = blockIdx.z;
    __shared__ float al[32 * 128];
    for (int idx = t; idx < 4096; idx += 256)
        al[idx] = attn[(size_t)b * 16384 + (c0 + (idx >> 7)) * 128 + (idx & 127)];
    __syncthreads();
    float acc[32];
#pragma unroll
    for (int k = 0; k < 32; k++) acc[k] = 0.f;
    for (int d = 0; d < 128; ++d) {
        float v = Bf[(((size_t)b * 128 + d) << 12) + n];
#pragma unroll
        for (int k = 0; k < 32; k++) acc[k] = fmaf(al[k * 128 + d], v, acc[k]);
    }
    float be = beta[0];
#pragma unroll
    for (int k = 0; k < 32; k++) {
        size_t idx = (((size_t)b * 128 + c0 + k) << 12) + n;
        outb[idx] = fmaf(be, acc[k], Bf[idx]);
    }
}

// ---- Final heads: 3x (1x1 conv 128->19 + sigmoid).  grid (16 n-tiles, 8 b) -
__global__ __launch_bounds__(256) void heads(
    const float* __restrict__ FP, const float* __restrict__ FC,
    const float* __restrict__ Wout, const float* __restrict__ bout,
    const float* __restrict__ Wp3, const float* __restrict__ bp3,
    const float* __restrict__ Wc3, const float* __restrict__ bc3,
    float* __restrict__ out)
{
    const int t = threadIdx.x;
    const int n = (blockIdx.x << 8) + t;
    const int b = blockIdx.y;
    __shared__ float wl[3 * 19 * 128];
    __shared__ float bl[3 * 19];
    for (int idx = t; idx < 2432; idx += 256) {
        wl[idx]        = Wout[idx];
        wl[2432 + idx] = Wp3[idx];
        wl[4864 + idx] = Wc3[idx];
    }
    if (t < 19) { bl[t] = bout[t]; bl[19 + t] = bp3[t]; bl[38 + t] = bc3[t]; }
    __syncthreads();
    float am[19], ap[19], ac[19];
#pragma unroll
    for (int o = 0; o < 19; o++) { am[o] = 0.f; ap[o] = 0.f; ac[o] = 0.f; }
    for (int chn = 0; chn < 128; ++chn) {
        float pv = FP[(((size_t)b * 128 + chn) << 12) + n];
        float cv = FC[(((size_t)b * 128 + chn) << 12) + n];
        float fv = pv + cv;
#pragma unroll
        for (int o = 0; o < 19; o++) {
            am[o] = fmaf(wl[o * 128 + chn], fv, am[o]);
            ap[o] = fmaf(wl[2432 + o * 128 + chn], pv, ap[o]);
            ac[o] = fmaf(wl[4864 + o * 128 + chn], cv, ac[o]);
        }
    }
    const size_t OS = (size_t)8 * 19 * 4096;
#pragma unroll
    for (int o = 0; o < 19; o++) {
        size_t base = (((size_t)b * 19 + o) << 12) + n;
        out[base]          = 1.f / (1.f + __expf(-(am[o] + bl[o])));
        out[OS + base]     = 1.f / (1.f + __expf(-(ap[o] + bl[19 + o])));
        out[2 * OS + base] = 1.f / (1.f + __expf(-(ac[o] + bl[38 + o])));
    }
}

extern "C" void kernel_launch(void* const* d_in, const int* in_sizes, int n_in,
                              void* d_out, int out_size, void* d_ws, size_t ws_size,
                              hipStream_t stream)
{
    const float* x     = (const float*)d_in[0];
    const float* Wp1   = (const float*)d_in[1];
    const float* bnp1  = (const float*)d_in[2];
    const float* Wc1   = (const float*)d_in[3];
    const float* bnc1  = (const float*)d_in[4];
    const float* Wb    = (const float*)d_in[5];
    const float* bb    = (const float*)d_in[6];
    const float* Wc    = (const float*)d_in[7];
    const float* bcv   = (const float*)d_in[8];
    const float* Wd    = (const float*)d_in[9];
    const float* bd    = (const float*)d_in[10];
    const float* alpha = (const float*)d_in[11];
    const float* beta  = (const float*)d_in[12];
    const float* Wp2   = (const float*)d_in[13];
    const float* bnp2  = (const float*)d_in[14];
    const float* Wc2   = (const float*)d_in[15];
    const float* bnc2  = (const float*)d_in[16];
    const float* Wout  = (const float*)d_in[17];
    const float* bo    = (const float*)d_in[18];
    const float* Wp3   = (const float*)d_in[19];
    const float* bp3   = (const float*)d_in[20];
    const float* Wc3   = (const float*)d_in[21];
    const float* bc3   = (const float*)d_in[22];
    float* out = (float*)d_out;

    char* ws = (char*)d_ws;
    const size_t S = (size_t)8 * 128 * 4096 * 4;   // 16 MB feature buffer
    float* bufA = (float*)(ws);                    // feat_p -> pam out -> Ccam
    float* bufD = (float*)(ws + S);                // d_ -> FP2
    float* bufB = (float*)(ws + 2 * S);            // feat_c -> FC2
    float* qb   = (float*)(ws + 3 * S);                              // b_ (2MB)
    float* kb   = (float*)(ws + 3 * S + (size_t)8 * 16 * 4096 * 4);  // c_ (2MB)
    float* egy  = (float*)(ws + 3 * S + (size_t)2 * 8 * 16 * 4096 * 4);

    dim3 blk(256);
    // P branch
    conv3x3_bnrelu<<<dim3(16, 4, 8), blk, 0, stream>>>(x, Wp1, bnp1, bufA, 512);
    pam_bc_1x1<<<dim3(16, 8), blk, 0, stream>>>(bufA, Wb, bb, Wc, bcv, qb, kb);
    pam_d_1x1<<<dim3(16, 4, 8), blk, 0, stream>>>(bufA, Wd, bd, bufD);
    pam_attn<<<dim3(128, 8), blk, 0, stream>>>(qb, kb, bufD, alpha, bufA);
    conv3x3_bnrelu<<<dim3(16, 4, 8), blk, 0, stream>>>(bufA, Wp2, bnp2, bufD, 128);
    // C branch
    conv3x3_bnrelu<<<dim3(16, 4, 8), blk, 0, stream>>>(x, Wc1, bnc1, bufB, 512);
    cam_energy<<<dim3(16, 8), blk, 0, stream>>>(bufB, egy);
    cam_softmax<<<dim3(8), dim3(128), 0, stream>>>(egy);
    cam_feat<<<dim3(16, 4, 8), blk, 0, stream>>>(egy, bufB, beta, bufA);
    conv3x3_bnrelu<<<dim3(16, 4, 8), blk, 0, stream>>>(bufA, Wc2, bnc2, bufB, 128);
    // fusion + heads
    heads<<<dim3(16, 8), blk, 0, stream>>>(bufD, bufB, Wout, bo, Wp3, bp3, Wc3, bc3, out);
}

// Round 2
// 2547.998 us; speedup vs baseline: 1.2783x; 1.2783x over previous
//
#include <hip/hip_runtime.h>
#include <math.h>

// ---------------------------------------------------------------------------
// DAHead: B=8, Cin=512, Ci=128, H=W=64, N=4096, Ck=16, NC=19.
// R2: PAM attention via bf16 MFMA (32x32x16), S^T orientation so softmax
//     state is per-lane. Convs still fp32 (next round).
// ws: bufA@0 (16MB), bufD@S (16MB, vb bf16 aliases its head), bufB@2S (16MB),
//     qt@3S (1MB), kt@+1MB, rowmax@+2MB (128KB), egy@+2.125MB (0.5MB)
// ---------------------------------------------------------------------------

typedef __attribute__((ext_vector_type(8)))  short short8;
typedef __attribute__((ext_vector_type(16))) float f32x16;

__device__ inline unsigned short f2bf(float f) {
    union { float f; unsigned u; } v; v.f = f;
    unsigned r = v.u + 0x7fffu + ((v.u >> 16) & 1u);   // RNE
    return (unsigned short)(r >> 16);
}

// ---- 3x3 conv (SAME) + folded-BN + ReLU (fp32, unchanged this round) ------
__global__ __launch_bounds__(256) void conv3x3_bnrelu(
    const float* __restrict__ x, const float* __restrict__ w,
    const float* __restrict__ bn, float* __restrict__ out, int Cin)
{
    const int t   = threadIdx.x;
    const int ts  = blockIdx.x;
    const int ty0 = (ts >> 2) << 4;
    const int tx0 = (ts & 3) << 4;
    const int co0 = blockIdx.y << 5;
    const int b   = blockIdx.z;

    const int q   = t & 63;
    const int qy  = q >> 3;
    const int qx  = q & 7;
    const int cog = t >> 6;

    __shared__ float ilds[8 * 18 * 19];
    __shared__ float wlds[8 * 9 * 32];

    float acc[2][2][8];
#pragma unroll
    for (int a0 = 0; a0 < 2; a0++)
#pragma unroll
        for (int a1 = 0; a1 < 2; a1++)
#pragma unroll
            for (int a2 = 0; a2 < 8; a2++) acc[a0][a1][a2] = 0.f;

    const int nchunks = Cin >> 3;
    for (int ch = 0; ch < nchunks; ++ch) {
        const int cin0 = ch << 3;
        for (int idx = t; idx < 8 * 18 * 18; idx += 256) {
            int cl  = idx / 324;
            int rem = idx - cl * 324;
            int r   = rem / 18;
            int c   = rem - r * 18;
            int gy  = ty0 + r - 1;
            int gx  = tx0 + c - 1;
            float v = 0.f;
            if ((unsigned)gy < 64u && (unsigned)gx < 64u)
                v = x[(((size_t)b * Cin + (cin0 + cl)) << 12) + (gy << 6) + gx];
            ilds[cl * 342 + r * 19 + c] = v;
        }
        for (int idx = t; idx < 8 * 9 * 32; idx += 256) {
            int col  = idx & 31;
            int rest = idx >> 5;
            int cl   = rest / 9;
            int kk   = rest - cl * 9;
            wlds[idx] = w[((size_t)(co0 + col) * Cin + cin0 + cl) * 9 + kk];
        }
        __syncthreads();

#pragma unroll 1
        for (int cl = 0; cl < 8; ++cl) {
            const float* ib = &ilds[cl * 342];
            const float* wb = &wlds[cl * 288];
#pragma unroll
            for (int ky = 0; ky < 3; ++ky) {
                const int r0 = 2 * qy + ky;
#pragma unroll
                for (int kx = 0; kx < 3; ++kx) {
                    float wv[8];
#pragma unroll
                    for (int ci = 0; ci < 8; ci++)
                        wv[ci] = wb[(ky * 3 + kx) * 32 + (cog << 3) + ci];
                    float i00 = ib[r0 * 19 + qx + kx];
                    float i01 = ib[r0 * 19 + qx + 8 + kx];
                    float i10 = ib[r0 * 19 + 19 + qx + kx];
                    float i11 = ib[r0 * 19 + 19 + qx + 8 + kx];
#pragma unroll
                    for (int ci = 0; ci < 8; ci++) {
                        acc[0][0][ci] = fmaf(i00, wv[ci], acc[0][0][ci]);
                        acc[0][1][ci] = fmaf(i01, wv[ci], acc[0][1][ci]);
                        acc[1][0][ci] = fmaf(i10, wv[ci], acc[1][0][ci]);
                        acc[1][1][ci] = fmaf(i11, wv[ci], acc[1][1][ci]);
                    }
                }
            }
        }
        __syncthreads();
    }

#pragma unroll
    for (int ci = 0; ci < 8; ci++) {
        int co = co0 + (cog << 3) + ci;
        float sc = bn[co], sh = bn[128 + co];
#pragma unroll
        for (int dy = 0; dy < 2; dy++) {
            int y = ty0 + 2 * qy + dy;
#pragma unroll
            for (int dx = 0; dx < 2; dx++) {
                int xx = tx0 + qx + 8 * dx;
                float v = fmaf(acc[dy][dx][ci], sc, sh);
                v = v > 0.f ? v : 0.f;
                out[(((size_t)b * 128 + co) << 12) + (y << 6) + xx] = v;
            }
        }
    }
}

// ---- PAM Q/K producer: q,k = W*A + b, emitted bf16 transposed [b][n][16] --
__global__ __launch_bounds__(256) void pam_qk_1x1(
    const float* __restrict__ A, const float* __restrict__ Wb, const float* __restrict__ bb,
    const float* __restrict__ Wc, const float* __restrict__ bc,
    unsigned short* __restrict__ qt, unsigned short* __restrict__ kt)
{
    __shared__ float wl[2 * 16 * 128];
    __shared__ float bl[32];
    const int t = threadIdx.x;
    const int n = (blockIdx.x << 8) + t;
    const int b = blockIdx.y;
    for (int idx = t; idx < 2048; idx += 256) { wl[idx] = Wb[idx]; wl[2048 + idx] = Wc[idx]; }
    if (t < 16) { bl[t] = bb[t]; bl[16 + t] = bc[t]; }
    __syncthreads();
    float ab[16], ac[16];
#pragma unroll
    for (int k = 0; k < 16; k++) { ab[k] = 0.f; ac[k] = 0.f; }
    for (int chn = 0; chn < 128; ++chn) {
        float a = A[(((size_t)b * 128 + chn) << 12) + n];
#pragma unroll
        for (int k = 0; k < 16; k++) {
            ab[k] = fmaf(wl[k * 128 + chn], a, ab[k]);
            ac[k] = fmaf(wl[2048 + k * 128 + chn], a, ac[k]);
        }
    }
    unsigned short uq[16], uk[16];
#pragma unroll
    for (int k = 0; k < 16; k++) {
        uq[k] = f2bf(ab[k] + bl[k]);
        uk[k] = f2bf(ac[k] + bl[16 + k]);
    }
    size_t row = (size_t)b * 4096 + n;      // 32B per row -> 2x uint4
    ((uint4*)qt)[row * 2 + 0] = ((uint4*)uq)[0];
    ((uint4*)qt)[row * 2 + 1] = ((uint4*)uq)[1];
    ((uint4*)kt)[row * 2 + 0] = ((uint4*)uk)[0];
    ((uint4*)kt)[row * 2 + 1] = ((uint4*)uk)[1];
}

// ---- PAM V producer: d_ = Wd*A + bd, emitted bf16 [b][c][4096] ------------
__global__ __launch_bounds__(256) void pam_v_1x1(
    const float* __restrict__ A, const float* __restrict__ Wd, const float* __restrict__ bd,
    unsigned short* __restrict__ vb)
{
    __shared__ float wl[32 * 128];
    __shared__ float bl[32];
    const int t   = threadIdx.x;
    const int n   = (blockIdx.x << 8) + t;
    const int co0 = blockIdx.y << 5;
    const int b   = blockIdx.z;
    for (int idx = t; idx < 4096; idx += 256) {
        int c2 = idx >> 7, chv = idx & 127;
        wl[idx] = Wd[(co0 + c2) * 128 + chv];
    }
    if (t < 32) bl[t] = bd[co0 + t];
    __syncthreads();
    float acc[32];
#pragma unroll
    for (int k = 0; k < 32; k++) acc[k] = 0.f;
    for (int chn = 0; chn < 128; ++chn) {
        float a = A[(((size_t)b * 128 + chn) << 12) + n];
#pragma unroll
        for (int k = 0; k < 32; k++) acc[k] = fmaf(wl[k * 128 + chn], a, acc[k]);
    }
#pragma unroll
    for (int k = 0; k < 32; k++)
        vb[(((size_t)b * 128 + co0 + k) << 12) + n] = f2bf(acc[k] + bl[k]);
}

// ---- PAM rowmax: rowmax[b][n] = max_m (q_n . k_m), via MFMA S^T tiles -----
// grid (128 n-tiles, 8 b), 256 thr. Wave w scans m-quarters (stride 128).
__global__ __launch_bounds__(256) void pam_rowmax(
    const unsigned short* __restrict__ qt, const unsigned short* __restrict__ kt,
    float* __restrict__ rowmax)
{
    const int t  = threadIdx.x;
    const int w  = t >> 6;
    const int L  = t & 63;
    const int ln = L & 31;
    const int g  = L >> 5;
    const int b  = blockIdx.y;
    const int n0 = blockIdx.x << 5;
    __shared__ float red[4][32];

    const f32x16 zero = {0,0,0,0,0,0,0,0,0,0,0,0,0,0,0,0};
    short8 qfrag = *(const short8*)(qt + (((size_t)b * 4096 + n0 + ln) << 4) + (g << 3));

    float mx = -INFINITY;
    for (int mq = (w << 5); mq < 4096; mq += 128) {
        short8 kfrag = *(const short8*)(kt + (((size_t)b * 4096 + mq + ln) << 4) + (g << 3));
        f32x16 s = __builtin_amdgcn_mfma_f32_32x32x16_bf16(kfrag, qfrag, zero, 0, 0, 0);
#pragma unroll
        for (int r = 0; r < 16; r++) mx = fmaxf(mx, s[r]);
    }
    mx = fmaxf(mx, __shfl_xor(mx, 32));
    if (L < 32) red[w][L] = mx;
    __syncthreads();
    if (t < 32) {
        float m = fmaxf(fmaxf(red[0][t], red[1][t]), fmaxf(red[2][t], red[3][t]));
        rowmax[((size_t)b << 12) + n0 + t] = m;
    }
}

// ---- PAM attention, MFMA. S^T = K.Q^T tiles -> per-lane softmax state.
// Block: 32 queries x 128 V-channels (wave w owns c-slice w*32).
// Per 128-m chunk: wave w computes S^T for its 32-m quarter, exp, shfl_xor(32)
// to PV-B-frag order, 2x ds_write_b128; then all waves do 8 PV MFMAs.
__global__ __launch_bounds__(256) void pam_attn_mfma(
    const unsigned short* __restrict__ qt, const unsigned short* __restrict__ kt,
    const unsigned short* __restrict__ vb, const float* __restrict__ rowmax,
    const float* __restrict__ alpha, float* __restrict__ Y)
{
    const int t  = threadIdx.x;
    const int w  = t >> 6;
    const int L  = t & 63;
    const int ln = L & 31;
    const int g  = L >> 5;
    const int b  = blockIdx.y;
    const int n0 = blockIdx.x << 5;
    const int c0 = w << 5;

    __shared__ unsigned short Pf[16 * 256];   // 16 segs x (32 lanes x 8 bf16)
    __shared__ float red[4][32];

    const f32x16 zero = {0,0,0,0,0,0,0,0,0,0,0,0,0,0,0,0};
    short8 qfrag = *(const short8*)(qt + (((size_t)b * 4096 + n0 + ln) << 4) + (g << 3));
    const float rm = rowmax[((size_t)b << 12) + n0 + ln];
    const float al = alpha[0];

    f32x16 acc = zero;
    float rs = 0.f;

    for (int m0 = 0; m0 < 4096; m0 += 128) {
        const int mq = m0 + (w << 5);
        short8 kfrag = *(const short8*)(kt + (((size_t)b * 4096 + mq + ln) << 4) + (g << 3));
        f32x16 s = __builtin_amdgcn_mfma_f32_32x32x16_bf16(kfrag, qfrag, zero, 0, 0, 0);

        float p[16];
#pragma unroll
        for (int r = 0; r < 16; r++) { p[r] = __expf(s[r] - rm); rs += p[r]; }
        float xx[16];
#pragma unroll
        for (int r = 0; r < 16; r++) xx[r] = __shfl_xor(p[r], 32);

        unsigned short f0[8], f1[8];
#pragma unroll
        for (int i = 0; i < 4; i++) {
            f0[i]     = f2bf(g ? xx[4 + i]  : p[i]);
            f0[4 + i] = f2bf(g ? p[4 + i]   : xx[i]);
            f1[i]     = f2bf(g ? xx[12 + i] : p[8 + i]);
            f1[4 + i] = f2bf(g ? p[12 + i]  : xx[8 + i]);
        }
        *(short8*)(&Pf[((w << 2) + g) * 256 + (ln << 3)])     = *(short8*)f0;
        *(short8*)(&Pf[((w << 2) + 2 + g) * 256 + (ln << 3)]) = *(short8*)f1;
        __syncthreads();

#pragma unroll
        for (int kk = 0; kk < 8; kk++) {
            short8 pfrag = *(const short8*)(&Pf[((kk << 1) + g) * 256 + (ln << 3)]);
            short8 vfrag = *(const short8*)(vb + (((size_t)b * 128 + c0 + ln) << 12)
                                               + m0 + (kk << 4) + (g << 3));
            acc = __builtin_amdgcn_mfma_f32_32x32x16_bf16(vfrag, pfrag, acc, 0, 0, 0);
        }
        __syncthreads();
    }

    rs += __shfl_xor(rs, 32);
    if (L < 32) red[w][L] = rs;
    __syncthreads();
    const float inv = 1.f / (red[0][ln] + red[1][ln] + red[2][ln] + red[3][ln]);
    const int n = n0 + ln;
#pragma unroll
    for (int r = 0; r < 16; r++) {
        int c = c0 + (r & 3) + ((r >> 2) << 3) + (g << 2);
        size_t idx = (((size_t)b * 128 + c) << 12) + n;
        Y[idx] = fmaf(al, acc[r] * inv, Y[idx]);
    }
}

// ---- CAM gram ----
__global__ __launch_bounds__(256) void cam_energy(
    const float* __restrict__ Bf, float* __restrict__ egy)
{
    const int t  = threadIdx.x;
    const int b  = blockIdx.y;
    const int i0 = (blockIdx.x >> 2) << 5;
    const int j0 = (blockIdx.x & 3) << 5;
    __shared__ float Bi[32 * 65], Bj[32 * 65];
    const int ig = t >> 4, jg = t & 15;
    float a00 = 0.f, a01 = 0.f, a10 = 0.f, a11 = 0.f;
    for (int nc = 0; nc < 4096; nc += 64) {
        for (int idx = t; idx < 2048; idx += 256) {
            int r = idx >> 6, n = idx & 63;
            Bi[r * 65 + n] = Bf[(((size_t)b * 128 + i0 + r) << 12) + nc + n];
            Bj[r * 65 + n] = Bf[(((size_t)b * 128 + j0 + r) << 12) + nc + n];
        }
        __syncthreads();
        for (int n = 0; n < 64; ++n) {
            float bi0 = Bi[(ig * 2 + 0) * 65 + n], bi1 = Bi[(ig * 2 + 1) * 65 + n];
            float bj0 = Bj[(jg * 2 + 0) * 65 + n], bj1 = Bj[(jg * 2 + 1) * 65 + n];
            a00 = fmaf(bi0, bj0, a00);
            a01 = fmaf(bi0, bj1, a01);
            a10 = fmaf(bi1, bj0, a10);
            a11 = fmaf(bi1, bj1, a11);
        }
        __syncthreads();
    }
    size_t base = (size_t)b * 16384;
    egy[base + (i0 + ig * 2 + 0) * 128 + (j0 + jg * 2 + 0)] = a00;
    egy[base + (i0 + ig * 2 + 0) * 128 + (j0 + jg * 2 + 1)] = a01;
    egy[base + (i0 + ig * 2 + 1) * 128 + (j0 + jg * 2 + 0)] = a10;
    egy[base + (i0 + ig * 2 + 1) * 128 + (j0 + jg * 2 + 1)] = a11;
}

// ---- CAM softmax of (rowmax - e), in place ----
__global__ __launch_bounds__(128) void cam_softmax(float* __restrict__ egy)
{
    const int b = blockIdx.x;
    const int i = threadIdx.x;
    float* row = egy + (size_t)b * 16384 + i * 128;
    float mn = INFINITY;
    for (int j = 0; j < 128; j++) mn = fminf(mn, row[j]);
    float s = 0.f;
    for (int j = 0; j < 128; j++) { float p = __expf(mn - row[j]); row[j] = p; s += p; }
    float inv = 1.f / s;
    for (int j = 0; j < 128; j++) row[j] *= inv;
}

// ---- CAM feat ----
__global__ __launch_bounds__(256) void cam_feat(
    const float* __restrict__ attn, const float* __restrict__ Bf,
    const float* __restrict__ beta, float* __restrict__ outb)
{
    const int t  = threadIdx.x;
    const int n  = (blockIdx.x << 8) + t;
    const int c0 = blockIdx.y << 5;
    const int b  = blockIdx.z;
    __shared__ float al[32 * 128];
    for (int idx = t; idx < 4096; idx += 256)
        al[idx] = attn[(size_t)b * 16384 + (c0 + (idx >> 7)) * 128 + (idx & 127)];
    __syncthreads();
    float acc[32];
#pragma unroll
    for (int k = 0; k < 32; k++) acc[k] = 0.f;
    for (int d = 0; d < 128; ++d) {
        float v = Bf[(((size_t)b * 128 + d) << 12) + n];
#pragma unroll
        for (int k = 0; k < 32; k++) acc[k] = fmaf(al[k * 128 + d], v, acc[k]);
    }
    float be = beta[0];
#pragma unroll
    for (int k = 0; k < 32; k++) {
        size_t idx = (((size_t)b * 128 + c0 + k) << 12) + n;
        outb[idx] = fmaf(be, acc[k], Bf[idx]);
    }
}

// ---- Final heads ----
__global__ __launch_bounds__(256) void heads(
    const float* __restrict__ FP, const float* __restrict__ FC,
    const float* __restrict__ Wout, const float* __restrict__ bout,
    const float* __restrict__ Wp3, const float* __restrict__ bp3,
    const float* __restrict__ Wc3, const float* __restrict__ bc3,
    float* __restrict__ out)
{
    const int t = threadIdx.x;
    const int n = (blockIdx.x << 8) + t;
    const int b = blockIdx.y;
    __shared__ float wl[3 * 19 * 128];
    __shared__ float bl[3 * 19];
    for (int idx = t; idx < 2432; idx += 256) {
        wl[idx]        = Wout[idx];
        wl[2432 + idx] = Wp3[idx];
        wl[4864 + idx] = Wc3[idx];
    }
    if (t < 19) { bl[t] = bout[t]; bl[19 + t] = bp3[t]; bl[38 + t] = bc3[t]; }
    __syncthreads();
    float am[19], ap[19], ac[19];
#pragma unroll
    for (int o = 0; o < 19; o++) { am[o] = 0.f; ap[o] = 0.f; ac[o] = 0.f; }
    for (int chn = 0; chn < 128; ++chn) {
        float pv = FP[(((size_t)b * 128 + chn) << 12) + n];
        float cv = FC[(((size_t)b * 128 + chn) << 12) + n];
        float fv = pv + cv;
#pragma unroll
        for (int o = 0; o < 19; o++) {
            am[o] = fmaf(wl[o * 128 + chn], fv, am[o]);
            ap[o] = fmaf(wl[2432 + o * 128 + chn], pv, ap[o]);
            ac[o] = fmaf(wl[4864 + o * 128 + chn], cv, ac[o]);
        }
    }
    const size_t OS = (size_t)8 * 19 * 4096;
#pragma unroll
    for (int o = 0; o < 19; o++) {
        size_t base = (((size_t)b * 19 + o) << 12) + n;
        out[base]          = 1.f / (1.f + __expf(-(am[o] + bl[o])));
        out[OS + base]     = 1.f / (1.f + __expf(-(ap[o] + bl[19 + o])));
        out[2 * OS + base] = 1.f / (1.f + __expf(-(ac[o] + bl[38 + o])));
    }
}

extern "C" void kernel_launch(void* const* d_in, const int* in_sizes, int n_in,
                              void* d_out, int out_size, void* d_ws, size_t ws_size,
                              hipStream_t stream)
{
    const float* x     = (const float*)d_in[0];
    const float* Wp1   = (const float*)d_in[1];
    const float* bnp1  = (const float*)d_in[2];
    const float* Wc1   = (const float*)d_in[3];
    const float* bnc1  = (const float*)d_in[4];
    const float* Wb    = (const float*)d_in[5];
    const float* bb    = (const float*)d_in[6];
    const float* Wc    = (const float*)d_in[7];
    const float* bcv   = (const float*)d_in[8];
    const float* Wd    = (const float*)d_in[9];
    const float* bd    = (const float*)d_in[10];
    const float* alpha = (const float*)d_in[11];
    const float* beta  = (const float*)d_in[12];
    const float* Wp2   = (const float*)d_in[13];
    const float* bnp2  = (const float*)d_in[14];
    const float* Wc2   = (const float*)d_in[15];
    const float* bnc2  = (const float*)d_in[16];
    const float* Wout  = (const float*)d_in[17];
    const float* bo    = (const float*)d_in[18];
    const float* Wp3   = (const float*)d_in[19];
    const float* bp3   = (const float*)d_in[20];
    const float* Wc3   = (const float*)d_in[21];
    const float* bc3   = (const float*)d_in[22];
    float* out = (float*)d_out;

    char* ws = (char*)d_ws;
    const size_t S = (size_t)8 * 128 * 4096 * 4;   // 16 MB feature buffer
    float* bufA = (float*)(ws);
    float* bufD = (float*)(ws + S);
    float* bufB = (float*)(ws + 2 * S);
    unsigned short* vb = (unsigned short*)(ws + S);          // aliases bufD head (bf16, 8MB)
    unsigned short* qt = (unsigned short*)(ws + 3 * S);                       // 1MB
    unsigned short* kt = (unsigned short*)(ws + 3 * S + (1u << 20));          // 1MB
    float* rowmax      = (float*)(ws + 3 * S + (2u << 20));                   // 128KB
    float* egy         = (float*)(ws + 3 * S + (2u << 20) + (1u << 17));      // 0.5MB

    dim3 blk(256);
    // P branch
    conv3x3_bnrelu<<<dim3(16, 4, 8), blk, 0, stream>>>(x, Wp1, bnp1, bufA, 512);
    pam_qk_1x1<<<dim3(16, 8), blk, 0, stream>>>(bufA, Wb, bb, Wc, bcv, qt, kt);
    pam_v_1x1<<<dim3(16, 4, 8), blk, 0, stream>>>(bufA, Wd, bd, vb);
    pam_rowmax<<<dim3(128, 8), blk, 0, stream>>>(qt, kt, rowmax);
    pam_attn_mfma<<<dim3(128, 8), blk, 0, stream>>>(qt, kt, vb, rowmax, alpha, bufA);
    conv3x3_bnrelu<<<dim3(16, 4, 8), blk, 0, stream>>>(bufA, Wp2, bnp2, bufD, 128);
    // C branch
    conv3x3_bnrelu<<<dim3(16, 4, 8), blk, 0, stream>>>(x, Wc1, bnc1, bufB, 512);
    cam_energy<<<dim3(16, 8), blk, 0, stream>>>(bufB, egy);
    cam_softmax<<<dim3(8), dim3(128), 0, stream>>>(egy);
    cam_feat<<<dim3(16, 4, 8), blk, 0, stream>>>(egy, bufB, beta, bufA);
    conv3x3_bnrelu<<<dim3(16, 4, 8), blk, 0, stream>>>(bufA, Wc2, bnc2, bufB, 128);
    // fusion + heads
    heads<<<dim3(16, 8), blk, 0, stream>>>(bufD, bufB, Wout, bo, Wp3, bp3, Wc3, bc3, out);
}

// Round 4
// 1024.085 us; speedup vs baseline: 3.1805x; 2.4881x over previous
//
#include <hip/hip_runtime.h>
#include <math.h>

// ---------------------------------------------------------------------------
// DAHead: B=8, Cin=512, Ci=128, H=W=64, N=4096, Ck=16, NC=19.
// R4: C-branch convs use hi/lo bf16-split MFMA (~fp32 accuracy) to fix
//     CAM-amplified quantization; P-branch convs stay plain bf16 MFMA.
// ws layout (byte offsets):
//   bufA@0 (16MB fp32: conv1p out, later conv2c out)
//   bufB@16M (16MB fp32: conv1c out)
//   bufD@32M (16MB fp32: conv2p out; head 8MB aliased as vb bf16 earlier)
//   pam_bf@48M (8MB bf16); camf@48M (16MB fp32, after pam_bf consumed)
//   qt@64M, kt@65M (1MB each), rowmax@66M (128K), egy@66M+128K (512K)
//   wp1@67M (1.125M), wc1h,wc1l (+1.125M each), wp2, wc2h, wc2l (288K each)
// ---------------------------------------------------------------------------

typedef __attribute__((ext_vector_type(8)))  short short8;
typedef __attribute__((ext_vector_type(16))) float f32x16;

__device__ inline unsigned short f2bf(float f) {
    union { float f; unsigned u; } v; v.f = f;
    unsigned r = v.u + 0x7fffu + ((v.u >> 16) & 1u);   // RNE
    return (unsigned short)(r >> 16);
}
__device__ inline float bf2f(unsigned short h) {
    union { unsigned u; float f; } v; v.u = ((unsigned)h) << 16;
    return v.f;
}

// ---- weight prepack: W[co][cin][9] fp32 -> wpack[chunk][tap][co][16] bf16 --
__global__ __launch_bounds__(256) void wpack_kernel(
    const float* __restrict__ W, unsigned short* __restrict__ wp, int Cin, int total)
{
    int idx = blockIdx.x * 256 + threadIdx.x;
    if (idx >= total) return;
    int chunk = idx / 18432;
    int rem   = idx - chunk * 18432;
    int tap   = rem >> 11;
    int rem2  = rem & 2047;
    int co    = rem2 >> 4;
    int ci    = rem2 & 15;
    int cin   = (chunk << 4) + ci;
    wp[idx] = f2bf(W[((size_t)co * Cin + cin) * 9 + tap]);
}

// ---- split weight prepack: hi = bf16(w), lo = bf16(w - hi) ----------------
__global__ __launch_bounds__(256) void wpack_split_kernel(
    const float* __restrict__ W, unsigned short* __restrict__ wph,
    unsigned short* __restrict__ wpl, int Cin, int total)
{
    int idx = blockIdx.x * 256 + threadIdx.x;
    if (idx >= total) return;
    int chunk = idx / 18432;
    int rem   = idx - chunk * 18432;
    int tap   = rem >> 11;
    int rem2  = rem & 2047;
    int co    = rem2 >> 4;
    int ci    = rem2 & 15;
    int cin   = (chunk << 4) + ci;
    float w = W[((size_t)co * Cin + cin) * 9 + tap];
    unsigned short hi = f2bf(w);
    wph[idx] = hi;
    wpl[idx] = f2bf(w - bf2f(hi));
}

// ---- 3x3 conv (SAME) + BN + ReLU via bf16 MFMA implicit GEMM --------------
// grid (32 row-pair tiles, 1, 8 b), 256 thr (4 waves, 2x2: wy=co-half, wx=row)
__global__ __launch_bounds__(256) void conv3x3_mfma(
    const void* __restrict__ xin, int in_is_fp32, int Cin,
    const unsigned short* __restrict__ wpack, const float* __restrict__ bn,
    float* __restrict__ out_f32, unsigned short* __restrict__ out_bf)
{
    const int t   = threadIdx.x;
    const int w   = t >> 6;
    const int wy  = w >> 1;
    const int wx  = w & 1;
    const int ln  = t & 63;
    const int l31 = ln & 31;
    const int g   = ln >> 5;
    const int y0  = blockIdx.x << 1;
    const int b   = blockIdx.z;

    __shared__ __align__(16) unsigned short Xl[4 * 66 * 16];
    __shared__ __align__(16) unsigned short Wl[9 * 128 * 16];

    const f32x16 zero = {0,0,0,0,0,0,0,0,0,0,0,0,0,0,0,0};
    f32x16 acc00 = zero, acc01 = zero, acc10 = zero, acc11 = zero;

    const int nchunks = Cin >> 4;
    for (int ch = 0; ch < nchunks; ++ch) {
        const int cin0 = ch << 4;
        for (int pid = t; pid < 264; pid += 256) {
            int r  = pid / 66;
            int xc = pid - r * 66;
            int gy = y0 - 1 + r;
            int gx = xc - 1;
            unsigned short tmp[16];
            if ((unsigned)gy < 64u && (unsigned)gx < 64u) {
                if (in_is_fp32) {
                    const float* src = (const float*)xin
                        + (((size_t)b * Cin + cin0) << 12) + (gy << 6) + gx;
#pragma unroll
                    for (int c = 0; c < 16; c++) tmp[c] = f2bf(src[(size_t)c << 12]);
                } else {
                    const unsigned short* src = (const unsigned short*)xin
                        + (((size_t)b * Cin + cin0) << 12) + (gy << 6) + gx;
#pragma unroll
                    for (int c = 0; c < 16; c++) tmp[c] = src[(size_t)c << 12];
                }
            } else {
#pragma unroll
                for (int c = 0; c < 16; c++) tmp[c] = 0;
            }
            *(uint4*)&Xl[pid * 16 + 0] = ((uint4*)tmp)[0];
            *(uint4*)&Xl[pid * 16 + 8] = ((uint4*)tmp)[1];
        }
        {
            const uint4* wsrc = (const uint4*)(wpack + (size_t)ch * 18432);
#pragma unroll
            for (int i = 0; i < 9; i++)
                ((uint4*)Wl)[t + (i << 8)] = wsrc[t + (i << 8)];
        }
        __syncthreads();

#pragma unroll 3
        for (int tap = 0; tap < 9; ++tap) {
            const int dy = tap / 3, dx = tap - dy * 3;
            short8 a0 = *(const short8*)&Wl[((tap << 7) + (wy << 6) + l31) * 16 + (g << 3)];
            short8 a1 = *(const short8*)&Wl[((tap << 7) + (wy << 6) + 32 + l31) * 16 + (g << 3)];
            const int row = wx + dy;
            short8 b0 = *(const short8*)&Xl[(row * 66 + l31 + dx) * 16 + (g << 3)];
            short8 b1 = *(const short8*)&Xl[(row * 66 + l31 + 32 + dx) * 16 + (g << 3)];
            acc00 = __builtin_amdgcn_mfma_f32_32x32x16_bf16(a0, b0, acc00, 0, 0, 0);
            acc01 = __builtin_amdgcn_mfma_f32_32x32x16_bf16(a0, b1, acc01, 0, 0, 0);
            acc10 = __builtin_amdgcn_mfma_f32_32x32x16_bf16(a1, b0, acc10, 0, 0, 0);
            acc11 = __builtin_amdgcn_mfma_f32_32x32x16_bf16(a1, b1, acc11, 0, 0, 0);
        }
        __syncthreads();
    }

    const int y = y0 + wx;
#pragma unroll
    for (int i = 0; i < 2; i++) {
#pragma unroll
        for (int j = 0; j < 2; j++) {
            const f32x16 a = (i == 0) ? (j == 0 ? acc00 : acc01)
                                      : (j == 0 ? acc10 : acc11);
#pragma unroll
            for (int r = 0; r < 16; r++) {
                int co = (wy << 6) + (i << 5) + (r & 3) + ((r >> 2) << 3) + (g << 2);
                int x  = (j << 5) + l31;
                float v = fmaf(a[r], bn[co], bn[128 + co]);
                v = v > 0.f ? v : 0.f;
                size_t o = (((size_t)b * 128 + co) << 12) + (y << 6) + x;
                if (out_f32) out_f32[o] = v;
                if (out_bf)  out_bf[o]  = f2bf(v);
            }
        }
    }
}

// ---- 3x3 conv, hi/lo split bf16 MFMA (~fp32 accuracy). fp32 input only. ---
// acc = Wh*Xh + Wh*Xl + Wl*Xh.  LDS ~90.6KB -> 1 block/CU.
__global__ __launch_bounds__(256) void conv3x3_mfma_hilo(
    const float* __restrict__ xin, int Cin,
    const unsigned short* __restrict__ wph, const unsigned short* __restrict__ wpl,
    const float* __restrict__ bn, float* __restrict__ out_f32)
{
    const int t   = threadIdx.x;
    const int w   = t >> 6;
    const int wy  = w >> 1;
    const int wx  = w & 1;
    const int ln  = t & 63;
    const int l31 = ln & 31;
    const int g   = ln >> 5;
    const int y0  = blockIdx.x << 1;
    const int b   = blockIdx.z;

    __shared__ __align__(16) unsigned short Xh[4 * 66 * 16];
    __shared__ __align__(16) unsigned short Xo[4 * 66 * 16];
    __shared__ __align__(16) unsigned short Wh[9 * 128 * 16];
    __shared__ __align__(16) unsigned short Wo[9 * 128 * 16];

    const f32x16 zero = {0,0,0,0,0,0,0,0,0,0,0,0,0,0,0,0};
    f32x16 acc00 = zero, acc01 = zero, acc10 = zero, acc11 = zero;

    const int nchunks = Cin >> 4;
    for (int ch = 0; ch < nchunks; ++ch) {
        const int cin0 = ch << 4;
        for (int pid = t; pid < 264; pid += 256) {
            int r  = pid / 66;
            int xc = pid - r * 66;
            int gy = y0 - 1 + r;
            int gx = xc - 1;
            unsigned short th[16], tl[16];
            if ((unsigned)gy < 64u && (unsigned)gx < 64u) {
                const float* src = xin + (((size_t)b * Cin + cin0) << 12) + (gy << 6) + gx;
#pragma unroll
                for (int c = 0; c < 16; c++) {
                    float f = src[(size_t)c << 12];
                    unsigned short hi = f2bf(f);
                    th[c] = hi;
                    tl[c] = f2bf(f - bf2f(hi));
                }
            } else {
#pragma unroll
                for (int c = 0; c < 16; c++) { th[c] = 0; tl[c] = 0; }
            }
            *(uint4*)&Xh[pid * 16 + 0] = ((uint4*)th)[0];
            *(uint4*)&Xh[pid * 16 + 8] = ((uint4*)th)[1];
            *(uint4*)&Xo[pid * 16 + 0] = ((uint4*)tl)[0];
            *(uint4*)&Xo[pid * 16 + 8] = ((uint4*)tl)[1];
        }
        {
            const uint4* sh = (const uint4*)(wph + (size_t)ch * 18432);
            const uint4* sl = (const uint4*)(wpl + (size_t)ch * 18432);
#pragma unroll
            for (int i = 0; i < 9; i++) {
                ((uint4*)Wh)[t + (i << 8)] = sh[t + (i << 8)];
                ((uint4*)Wo)[t + (i << 8)] = sl[t + (i << 8)];
            }
        }
        __syncthreads();

#pragma unroll 1
        for (int tap = 0; tap < 9; ++tap) {
            const int dy = tap / 3, dx = tap - dy * 3;
            const int wi0 = ((tap << 7) + (wy << 6) + l31) * 16 + (g << 3);
            const int wi1 = ((tap << 7) + (wy << 6) + 32 + l31) * 16 + (g << 3);
            const int row = wx + dy;
            const int xi0 = (row * 66 + l31 + dx) * 16 + (g << 3);
            const int xi1 = (row * 66 + l31 + 32 + dx) * 16 + (g << 3);
            short8 a0h = *(const short8*)&Wh[wi0];
            short8 a1h = *(const short8*)&Wh[wi1];
            short8 a0l = *(const short8*)&Wo[wi0];
            short8 a1l = *(const short8*)&Wo[wi1];
            short8 b0h = *(const short8*)&Xh[xi0];
            short8 b1h = *(const short8*)&Xh[xi1];
            short8 b0l = *(const short8*)&Xo[xi0];
            short8 b1l = *(const short8*)&Xo[xi1];
            acc00 = __builtin_amdgcn_mfma_f32_32x32x16_bf16(a0h, b0h, acc00, 0, 0, 0);
            acc01 = __builtin_amdgcn_mfma_f32_32x32x16_bf16(a0h, b1h, acc01, 0, 0, 0);
            acc10 = __builtin_amdgcn_mfma_f32_32x32x16_bf16(a1h, b0h, acc10, 0, 0, 0);
            acc11 = __builtin_amdgcn_mfma_f32_32x32x16_bf16(a1h, b1h, acc11, 0, 0, 0);
            acc00 = __builtin_amdgcn_mfma_f32_32x32x16_bf16(a0h, b0l, acc00, 0, 0, 0);
            acc01 = __builtin_amdgcn_mfma_f32_32x32x16_bf16(a0h, b1l, acc01, 0, 0, 0);
            acc10 = __builtin_amdgcn_mfma_f32_32x32x16_bf16(a1h, b0l, acc10, 0, 0, 0);
            acc11 = __builtin_amdgcn_mfma_f32_32x32x16_bf16(a1h, b1l, acc11, 0, 0, 0);
            acc00 = __builtin_amdgcn_mfma_f32_32x32x16_bf16(a0l, b0h, acc00, 0, 0, 0);
            acc01 = __builtin_amdgcn_mfma_f32_32x32x16_bf16(a0l, b1h, acc01, 0, 0, 0);
            acc10 = __builtin_amdgcn_mfma_f32_32x32x16_bf16(a1l, b0h, acc10, 0, 0, 0);
            acc11 = __builtin_amdgcn_mfma_f32_32x32x16_bf16(a1l, b1h, acc11, 0, 0, 0);
        }
        __syncthreads();
    }

    const int y = y0 + wx;
#pragma unroll
    for (int i = 0; i < 2; i++) {
#pragma unroll
        for (int j = 0; j < 2; j++) {
            const f32x16 a = (i == 0) ? (j == 0 ? acc00 : acc01)
                                      : (j == 0 ? acc10 : acc11);
#pragma unroll
            for (int r = 0; r < 16; r++) {
                int co = (wy << 6) + (i << 5) + (r & 3) + ((r >> 2) << 3) + (g << 2);
                int x  = (j << 5) + l31;
                float v = fmaf(a[r], bn[co], bn[128 + co]);
                v = v > 0.f ? v : 0.f;
                out_f32[(((size_t)b * 128 + co) << 12) + (y << 6) + x] = v;
            }
        }
    }
}

// ---- PAM Q/K producer ----
__global__ __launch_bounds__(256) void pam_qk_1x1(
    const float* __restrict__ A, const float* __restrict__ Wb, const float* __restrict__ bb,
    const float* __restrict__ Wc, const float* __restrict__ bc,
    unsigned short* __restrict__ qt, unsigned short* __restrict__ kt)
{
    __shared__ float wl[2 * 16 * 128];
    __shared__ float bl[32];
    const int t = threadIdx.x;
    const int n = (blockIdx.x << 8) + t;
    const int b = blockIdx.y;
    for (int idx = t; idx < 2048; idx += 256) { wl[idx] = Wb[idx]; wl[2048 + idx] = Wc[idx]; }
    if (t < 16) { bl[t] = bb[t]; bl[16 + t] = bc[t]; }
    __syncthreads();
    float ab[16], ac[16];
#pragma unroll
    for (int k = 0; k < 16; k++) { ab[k] = 0.f; ac[k] = 0.f; }
    for (int chn = 0; chn < 128; ++chn) {
        float a = A[(((size_t)b * 128 + chn) << 12) + n];
#pragma unroll
        for (int k = 0; k < 16; k++) {
            ab[k] = fmaf(wl[k * 128 + chn], a, ab[k]);
            ac[k] = fmaf(wl[2048 + k * 128 + chn], a, ac[k]);
        }
    }
    unsigned short uq[16], uk[16];
#pragma unroll
    for (int k = 0; k < 16; k++) {
        uq[k] = f2bf(ab[k] + bl[k]);
        uk[k] = f2bf(ac[k] + bl[16 + k]);
    }
    size_t row = (size_t)b * 4096 + n;
    ((uint4*)qt)[row * 2 + 0] = ((uint4*)uq)[0];
    ((uint4*)qt)[row * 2 + 1] = ((uint4*)uq)[1];
    ((uint4*)kt)[row * 2 + 0] = ((uint4*)uk)[0];
    ((uint4*)kt)[row * 2 + 1] = ((uint4*)uk)[1];
}

// ---- PAM V producer ----
__global__ __launch_bounds__(256) void pam_v_1x1(
    const float* __restrict__ A, const float* __restrict__ Wd, const float* __restrict__ bd,
    unsigned short* __restrict__ vb)
{
    __shared__ float wl[32 * 128];
    __shared__ float bl[32];
    const int t   = threadIdx.x;
    const int n   = (blockIdx.x << 8) + t;
    const int co0 = blockIdx.y << 5;
    const int b   = blockIdx.z;
    for (int idx = t; idx < 4096; idx += 256) {
        int c2 = idx >> 7, chv = idx & 127;
        wl[idx] = Wd[(co0 + c2) * 128 + chv];
    }
    if (t < 32) bl[t] = bd[co0 + t];
    __syncthreads();
    float acc[32];
#pragma unroll
    for (int k = 0; k < 32; k++) acc[k] = 0.f;
    for (int chn = 0; chn < 128; ++chn) {
        float a = A[(((size_t)b * 128 + chn) << 12) + n];
#pragma unroll
        for (int k = 0; k < 32; k++) acc[k] = fmaf(wl[k * 128 + chn], a, acc[k]);
    }
#pragma unroll
    for (int k = 0; k < 32; k++)
        vb[(((size_t)b * 128 + co0 + k) << 12) + n] = f2bf(acc[k] + bl[k]);
}

// ---- PAM rowmax ----
__global__ __launch_bounds__(256) void pam_rowmax(
    const unsigned short* __restrict__ qt, const unsigned short* __restrict__ kt,
    float* __restrict__ rowmax)
{
    const int t  = threadIdx.x;
    const int w  = t >> 6;
    const int L  = t & 63;
    const int ln = L & 31;
    const int g  = L >> 5;
    const int b  = blockIdx.y;
    const int n0 = blockIdx.x << 5;
    __shared__ float red[4][32];

    const f32x16 zero = {0,0,0,0,0,0,0,0,0,0,0,0,0,0,0,0};
    short8 qfrag = *(const short8*)(qt + (((size_t)b * 4096 + n0 + ln) << 4) + (g << 3));

    float mx = -INFINITY;
    for (int mq = (w << 5); mq < 4096; mq += 128) {
        short8 kfrag = *(const short8*)(kt + (((size_t)b * 4096 + mq + ln) << 4) + (g << 3));
        f32x16 s = __builtin_amdgcn_mfma_f32_32x32x16_bf16(kfrag, qfrag, zero, 0, 0, 0);
#pragma unroll
        for (int r = 0; r < 16; r++) mx = fmaxf(mx, s[r]);
    }
    mx = fmaxf(mx, __shfl_xor(mx, 32));
    if (L < 32) red[w][L] = mx;
    __syncthreads();
    if (t < 32) {
        float m = fmaxf(fmaxf(red[0][t], red[1][t]), fmaxf(red[2][t], red[3][t]));
        rowmax[((size_t)b << 12) + n0 + t] = m;
    }
}

// ---- PAM attention, MFMA; out = bf16 (feeds conv2p) -----------------------
__global__ __launch_bounds__(256) void pam_attn_mfma(
    const unsigned short* __restrict__ qt, const unsigned short* __restrict__ kt,
    const unsigned short* __restrict__ vb, const float* __restrict__ rowmax,
    const float* __restrict__ alpha, const float* __restrict__ Y,
    unsigned short* __restrict__ outb)
{
    const int t  = threadIdx.x;
    const int w  = t >> 6;
    const int L  = t & 63;
    const int ln = L & 31;
    const int g  = L >> 5;
    const int b  = blockIdx.y;
    const int n0 = blockIdx.x << 5;
    const int c0 = w << 5;

    __shared__ unsigned short Pf[16 * 256];
    __shared__ float red[4][32];

    const f32x16 zero = {0,0,0,0,0,0,0,0,0,0,0,0,0,0,0,0};
    short8 qfrag = *(const short8*)(qt + (((size_t)b * 4096 + n0 + ln) << 4) + (g << 3));
    const float rm = rowmax[((size_t)b << 12) + n0 + ln];
    const float al = alpha[0];

    f32x16 acc = zero;
    float rs = 0.f;

    for (int m0 = 0; m0 < 4096; m0 += 128) {
        const int mq = m0 + (w << 5);
        short8 kfrag = *(const short8*)(kt + (((size_t)b * 4096 + mq + ln) << 4) + (g << 3));
        f32x16 s = __builtin_amdgcn_mfma_f32_32x32x16_bf16(kfrag, qfrag, zero, 0, 0, 0);

        float p[16];
#pragma unroll
        for (int r = 0; r < 16; r++) { p[r] = __expf(s[r] - rm); rs += p[r]; }
        float xx[16];
#pragma unroll
        for (int r = 0; r < 16; r++) xx[r] = __shfl_xor(p[r], 32);

        unsigned short f0[8], f1[8];
#pragma unroll
        for (int i = 0; i < 4; i++) {
            f0[i]     = f2bf(g ? xx[4 + i]  : p[i]);
            f0[4 + i] = f2bf(g ? p[4 + i]   : xx[i]);
            f1[i]     = f2bf(g ? xx[12 + i] : p[8 + i]);
            f1[4 + i] = f2bf(g ? p[12 + i]  : xx[8 + i]);
        }
        *(short8*)(&Pf[((w << 2) + g) * 256 + (ln << 3)])     = *(short8*)f0;
        *(short8*)(&Pf[((w << 2) + 2 + g) * 256 + (ln << 3)]) = *(short8*)f1;
        __syncthreads();

#pragma unroll
        for (int kk = 0; kk < 8; kk++) {
            short8 pfrag = *(const short8*)(&Pf[((kk << 1) + g) * 256 + (ln << 3)]);
            short8 vfrag = *(const short8*)(vb + (((size_t)b * 128 + c0 + ln) << 12)
                                               + m0 + (kk << 4) + (g << 3));
            acc = __builtin_amdgcn_mfma_f32_32x32x16_bf16(vfrag, pfrag, acc, 0, 0, 0);
        }
        __syncthreads();
    }

    rs += __shfl_xor(rs, 32);
    if (L < 32) red[w][L] = rs;
    __syncthreads();
    const float inv = 1.f / (red[0][ln] + red[1][ln] + red[2][ln] + red[3][ln]);
    const int n = n0 + ln;
#pragma unroll
    for (int r = 0; r < 16; r++) {
        int c = c0 + (r & 3) + ((r >> 2) << 3) + (g << 2);
        size_t idx = (((size_t)b * 128 + c) << 12) + n;
        outb[idx] = f2bf(fmaf(al, acc[r] * inv, Y[idx]));
    }
}

// ---- CAM gram (fp32) ----
__global__ __launch_bounds__(256) void cam_energy(
    const float* __restrict__ Bf, float* __restrict__ egy)
{
    const int t  = threadIdx.x;
    const int b  = blockIdx.y;
    const int i0 = (blockIdx.x >> 2) << 5;
    const int j0 = (blockIdx.x & 3) << 5;
    __shared__ float Bi[32 * 65], Bj[32 * 65];
    const int ig = t >> 4, jg = t & 15;
    float a00 = 0.f, a01 = 0.f, a10 = 0.f, a11 = 0.f;
    for (int nc = 0; nc < 4096; nc += 64) {
        for (int idx = t; idx < 2048; idx += 256) {
            int r = idx >> 6, n = idx & 63;
            Bi[r * 65 + n] = Bf[(((size_t)b * 128 + i0 + r) << 12) + nc + n];
            Bj[r * 65 + n] = Bf[(((size_t)b * 128 + j0 + r) << 12) + nc + n];
        }
        __syncthreads();
        for (int n = 0; n < 64; ++n) {
            float bi0 = Bi[(ig * 2 + 0) * 65 + n], bi1 = Bi[(ig * 2 + 1) * 65 + n];
            float bj0 = Bj[(jg * 2 + 0) * 65 + n], bj1 = Bj[(jg * 2 + 1) * 65 + n];
            a00 = fmaf(bi0, bj0, a00);
            a01 = fmaf(bi0, bj1, a01);
            a10 = fmaf(bi1, bj0, a10);
            a11 = fmaf(bi1, bj1, a11);
        }
        __syncthreads();
    }
    size_t base = (size_t)b * 16384;
    egy[base + (i0 + ig * 2 + 0) * 128 + (j0 + jg * 2 + 0)] = a00;
    egy[base + (i0 + ig * 2 + 0) * 128 + (j0 + jg * 2 + 1)] = a01;
    egy[base + (i0 + ig * 2 + 1) * 128 + (j0 + jg * 2 + 0)] = a10;
    egy[base + (i0 + ig * 2 + 1) * 128 + (j0 + jg * 2 + 1)] = a11;
}

// ---- CAM softmax of (rowmax - e), in place ----
__global__ __launch_bounds__(128) void cam_softmax(float* __restrict__ egy)
{
    const int b = blockIdx.x;
    const int i = threadIdx.x;
    float* row = egy + (size_t)b * 16384 + i * 128;
    float mn = INFINITY;
    for (int j = 0; j < 128; j++) mn = fminf(mn, row[j]);
    float s = 0.f;
    for (int j = 0; j < 128; j++) { float p = __expf(mn - row[j]); row[j] = p; s += p; }
    float inv = 1.f / s;
    for (int j = 0; j < 128; j++) row[j] *= inv;
}

// ---- CAM feat: fp32 out (feeds conv2c hilo) ----
__global__ __launch_bounds__(256) void cam_feat(
    const float* __restrict__ attn, const float* __restrict__ Bf,
    const float* __restrict__ beta, float* __restrict__ outf)
{
    const int t  = threadIdx.x;
    const int n  = (blockIdx.x << 8) + t;
    const int c0 = blockIdx.y << 5;
    const int b  = blockIdx.z;
    __shared__ float al[32 * 128];
    for (int idx = t; idx < 4096; idx += 256)
        al[idx] = attn[(size_t)b * 16384 + (c0 + (idx >> 7)) * 128 + (idx & 127)];
    __syncthreads();
    float acc[32];
#pragma unroll
    for (int k = 0; k < 32; k++) acc[k] = 0.f;
    for (int d = 0; d < 128; ++d) {
        float v = Bf[(((size_t)b * 128 + d) << 12) + n];
#pragma unroll
        for (int k = 0; k < 32; k++) acc[k] = fmaf(al[k * 128 + d], v, acc[k]);
    }
    float be = beta[0];
#pragma unroll
    for (int k = 0; k < 32; k++) {
        size_t idx = (((size_t)b * 128 + c0 + k) << 12) + n;
        outf[idx] = fmaf(be, acc[k], Bf[idx]);
    }
}

// ---- Final heads ----
__global__ __launch_bounds__(256) void heads(
    const float* __restrict__ FP, const float* __restrict__ FC,
    const float* __restrict__ Wout, const float* __restrict__ bout,
    const float* __restrict__ Wp3, const float* __restrict__ bp3,
    const float* __restrict__ Wc3, const float* __restrict__ bc3,
    float* __restrict__ out)
{
    const int t = threadIdx.x;
    const int n = (blockIdx.x << 8) + t;
    const int b = blockIdx.y;
    __shared__ float wl[3 * 19 * 128];
    __shared__ float bl[3 * 19];
    for (int idx = t; idx < 2432; idx += 256) {
        wl[idx]        = Wout[idx];
        wl[2432 + idx] = Wp3[idx];
        wl[4864 + idx] = Wc3[idx];
    }
    if (t < 19) { bl[t] = bout[t]; bl[19 + t] = bp3[t]; bl[38 + t] = bc3[t]; }
    __syncthreads();
    float am[19], ap[19], ac[19];
#pragma unroll
    for (int o = 0; o < 19; o++) { am[o] = 0.f; ap[o] = 0.f; ac[o] = 0.f; }
    for (int chn = 0; chn < 128; ++chn) {
        float pv = FP[(((size_t)b * 128 + chn) << 12) + n];
        float cv = FC[(((size_t)b * 128 + chn) << 12) + n];
        float fv = pv + cv;
#pragma unroll
        for (int o = 0; o < 19; o++) {
            am[o] = fmaf(wl[o * 128 + chn], fv, am[o]);
            ap[o] = fmaf(wl[2432 + o * 128 + chn], pv, ap[o]);
            ac[o] = fmaf(wl[4864 + o * 128 + chn], cv, ac[o]);
        }
    }
    const size_t OS = (size_t)8 * 19 * 4096;
#pragma unroll
    for (int o = 0; o < 19; o++) {
        size_t base = (((size_t)b * 19 + o) << 12) + n;
        out[base]          = 1.f / (1.f + __expf(-(am[o] + bl[o])));
        out[OS + base]     = 1.f / (1.f + __expf(-(ap[o] + bl[19 + o])));
        out[2 * OS + base] = 1.f / (1.f + __expf(-(ac[o] + bl[38 + o])));
    }
}

extern "C" void kernel_launch(void* const* d_in, const int* in_sizes, int n_in,
                              void* d_out, int out_size, void* d_ws, size_t ws_size,
                              hipStream_t stream)
{
    const float* x     = (const float*)d_in[0];
    const float* Wp1   = (const float*)d_in[1];
    const float* bnp1  = (const float*)d_in[2];
    const float* Wc1   = (const float*)d_in[3];
    const float* bnc1  = (const float*)d_in[4];
    const float* Wb    = (const float*)d_in[5];
    const float* bb    = (const float*)d_in[6];
    const float* Wc    = (const float*)d_in[7];
    const float* bcv   = (const float*)d_in[8];
    const float* Wd    = (const float*)d_in[9];
    const float* bd    = (const float*)d_in[10];
    const float* alpha = (const float*)d_in[11];
    const float* beta  = (const float*)d_in[12];
    const float* Wp2   = (const float*)d_in[13];
    const float* bnp2  = (const float*)d_in[14];
    const float* Wc2   = (const float*)d_in[15];
    const float* bnc2  = (const float*)d_in[16];
    const float* Wout  = (const float*)d_in[17];
    const float* bo    = (const float*)d_in[18];
    const float* Wp3   = (const float*)d_in[19];
    const float* bp3   = (const float*)d_in[20];
    const float* Wc3   = (const float*)d_in[21];
    const float* bc3   = (const float*)d_in[22];
    float* out = (float*)d_out;

    char* ws = (char*)d_ws;
    const size_t MB = 1u << 20;
    const size_t W1SZ = (size_t)32 * 18432 * 2;   // 1.125 MB
    const size_t W2SZ = (size_t)8 * 18432 * 2;    // 288 KB
    float*          bufA   = (float*)(ws);                     // conv1p out; later conv2c out
    float*          bufB   = (float*)(ws + 16 * MB);           // conv1c out
    float*          bufD   = (float*)(ws + 32 * MB);           // conv2p out
    unsigned short* vb     = (unsigned short*)(ws + 32 * MB);  // aliases bufD head
    unsigned short* pam_bf = (unsigned short*)(ws + 48 * MB);
    float*          camf   = (float*)(ws + 48 * MB);           // after pam_bf consumed
    unsigned short* qt     = (unsigned short*)(ws + 64 * MB);
    unsigned short* kt     = (unsigned short*)(ws + 65 * MB);
    float*          rowmax = (float*)(ws + 66 * MB);
    float*          egy    = (float*)(ws + 66 * MB + (1u << 17));
    unsigned short* wp1    = (unsigned short*)(ws + 67 * MB);
    unsigned short* wc1h   = (unsigned short*)(ws + 67 * MB + W1SZ);
    unsigned short* wc1l   = (unsigned short*)(ws + 67 * MB + 2 * W1SZ);
    unsigned short* wp2    = (unsigned short*)(ws + 67 * MB + 3 * W1SZ);
    unsigned short* wc2h   = (unsigned short*)(ws + 67 * MB + 3 * W1SZ + W2SZ);
    unsigned short* wc2l   = (unsigned short*)(ws + 67 * MB + 3 * W1SZ + 2 * W2SZ);

    dim3 blk(256);
    const int n1 = 32 * 18432;
    const int n2 = 8 * 18432;
    wpack_kernel<<<dim3((n1 + 255) / 256), blk, 0, stream>>>(Wp1, wp1, 512, n1);
    wpack_kernel<<<dim3((n2 + 255) / 256), blk, 0, stream>>>(Wp2, wp2, 128, n2);
    wpack_split_kernel<<<dim3((n1 + 255) / 256), blk, 0, stream>>>(Wc1, wc1h, wc1l, 512, n1);
    wpack_split_kernel<<<dim3((n2 + 255) / 256), blk, 0, stream>>>(Wc2, wc2h, wc2l, 128, n2);

    // P branch (plain bf16 MFMA)
    conv3x3_mfma<<<dim3(32, 1, 8), blk, 0, stream>>>(x, 1, 512, wp1, bnp1, bufA, (unsigned short*)0);
    pam_qk_1x1<<<dim3(16, 8), blk, 0, stream>>>(bufA, Wb, bb, Wc, bcv, qt, kt);
    pam_v_1x1<<<dim3(16, 4, 8), blk, 0, stream>>>(bufA, Wd, bd, vb);
    pam_rowmax<<<dim3(128, 8), blk, 0, stream>>>(qt, kt, rowmax);
    pam_attn_mfma<<<dim3(128, 8), blk, 0, stream>>>(qt, kt, vb, rowmax, alpha, bufA, pam_bf);
    conv3x3_mfma<<<dim3(32, 1, 8), blk, 0, stream>>>(pam_bf, 0, 128, wp2, bnp2, bufD, (unsigned short*)0);
    // C branch (hi/lo split MFMA, ~fp32)
    conv3x3_mfma_hilo<<<dim3(32, 1, 8), blk, 0, stream>>>(x, 512, wc1h, wc1l, bnc1, bufB);
    cam_energy<<<dim3(16, 8), blk, 0, stream>>>(bufB, egy);
    cam_softmax<<<dim3(8), dim3(128), 0, stream>>>(egy);
    cam_feat<<<dim3(16, 4, 8), blk, 0, stream>>>(egy, bufB, beta, camf);
    conv3x3_mfma_hilo<<<dim3(32, 1, 8), blk, 0, stream>>>(camf, 128, wc2h, wc2l, bnc2, bufA);
    // fusion + heads
    heads<<<dim3(16, 8), blk, 0, stream>>>(bufD, bufA, Wout, bo, Wp3, bp3, Wc3, bc3, out);
}

// Round 5
// 841.559 us; speedup vs baseline: 3.8703x; 1.2169x over previous
//
#include <hip/hip_runtime.h>
#include <math.h>

// ---------------------------------------------------------------------------
// DAHead: B=8, Cin=512, Ci=128, H=W=64, N=4096, Ck=16, NC=19.
// R5: cam_energy -> hi/lo bf16 MFMA Gram with n-split (1024 blocks) + fused
//     parallel softmax; convs co-split (grid x2, hilo LDS 90->54KB).
// ws (byte offsets):
//   bufA@0 (16MB fp32)  bufB@16M (16MB fp32)
//   vb@32M (8MB bf16)   egy_part@40M (4MB fp32)   [both dead before conv2p]
//   bufD@32M (16MB fp32, conv2p out)
//   bh@48M, bl@56M (8MB bf16 each)  ->  pam_bf@48M (8MB)  ->  camf@48M (16MB)
//   qt@64M, kt@65M, rowmax@66M, egy@66M+128K
//   wp1@67M, wc1h, wc1l (1.125MB each), wp2, wc2h, wc2l (288KB each)
// ---------------------------------------------------------------------------

typedef __attribute__((ext_vector_type(8)))  short short8;
typedef __attribute__((ext_vector_type(16))) float f32x16;

__device__ inline unsigned short f2bf(float f) {
    union { float f; unsigned u; } v; v.f = f;
    unsigned r = v.u + 0x7fffu + ((v.u >> 16) & 1u);   // RNE
    return (unsigned short)(r >> 16);
}
__device__ inline float bf2f(unsigned short h) {
    union { unsigned u; float f; } v; v.u = ((unsigned)h) << 16;
    return v.f;
}

// ---- weight prepack: W[co][cin][9] fp32 -> wpack[chunk][tap][co128][16] ---
__global__ __launch_bounds__(256) void wpack_kernel(
    const float* __restrict__ W, unsigned short* __restrict__ wp, int Cin, int total)
{
    int idx = blockIdx.x * 256 + threadIdx.x;
    if (idx >= total) return;
    int chunk = idx / 18432;
    int rem   = idx - chunk * 18432;
    int tap   = rem >> 11;
    int rem2  = rem & 2047;
    int co    = rem2 >> 4;
    int ci    = rem2 & 15;
    int cin   = (chunk << 4) + ci;
    wp[idx] = f2bf(W[((size_t)co * Cin + cin) * 9 + tap]);
}

__global__ __launch_bounds__(256) void wpack_split_kernel(
    const float* __restrict__ W, unsigned short* __restrict__ wph,
    unsigned short* __restrict__ wpl, int Cin, int total)
{
    int idx = blockIdx.x * 256 + threadIdx.x;
    if (idx >= total) return;
    int chunk = idx / 18432;
    int rem   = idx - chunk * 18432;
    int tap   = rem >> 11;
    int rem2  = rem & 2047;
    int co    = rem2 >> 4;
    int ci    = rem2 & 15;
    int cin   = (chunk << 4) + ci;
    float w = W[((size_t)co * Cin + cin) * 9 + tap];
    unsigned short hi = f2bf(w);
    wph[idx] = hi;
    wpl[idx] = f2bf(w - bf2f(hi));
}

// ---- 3x3 conv + BN + ReLU, bf16 MFMA, co-split. grid (32, 2, 8) -----------
__global__ __launch_bounds__(256) void conv3x3_mfma(
    const void* __restrict__ xin, int in_is_fp32, int Cin,
    const unsigned short* __restrict__ wpack, const float* __restrict__ bn,
    float* __restrict__ out_f32, unsigned short* __restrict__ out_bf)
{
    const int t   = threadIdx.x;
    const int w   = t >> 6;
    const int wy  = w >> 1;           // co 32-half within this block's 64
    const int wx  = w & 1;            // output row
    const int ln  = t & 63;
    const int l31 = ln & 31;
    const int g   = ln >> 5;
    const int y0  = blockIdx.x << 1;
    const int co0 = blockIdx.y << 6;  // 0 or 64
    const int b   = blockIdx.z;

    __shared__ __align__(16) unsigned short Xl[4 * 66 * 16];   // 8448 B
    __shared__ __align__(16) unsigned short Wl[9 * 64 * 16];   // 18432 B

    const f32x16 zero = {0,0,0,0,0,0,0,0,0,0,0,0,0,0,0,0};
    f32x16 acc0 = zero, acc1 = zero;

    const int nchunks = Cin >> 4;
    for (int ch = 0; ch < nchunks; ++ch) {
        const int cin0 = ch << 4;
        for (int pid = t; pid < 264; pid += 256) {
            int r  = pid / 66;
            int xc = pid - r * 66;
            int gy = y0 - 1 + r;
            int gx = xc - 1;
            unsigned short tmp[16];
            if ((unsigned)gy < 64u && (unsigned)gx < 64u) {
                if (in_is_fp32) {
                    const float* src = (const float*)xin
                        + (((size_t)b * Cin + cin0) << 12) + (gy << 6) + gx;
#pragma unroll
                    for (int c = 0; c < 16; c++) tmp[c] = f2bf(src[(size_t)c << 12]);
                } else {
                    const unsigned short* src = (const unsigned short*)xin
                        + (((size_t)b * Cin + cin0) << 12) + (gy << 6) + gx;
#pragma unroll
                    for (int c = 0; c < 16; c++) tmp[c] = src[(size_t)c << 12];
                }
            } else {
#pragma unroll
                for (int c = 0; c < 16; c++) tmp[c] = 0;
            }
            *(uint4*)&Xl[pid * 16 + 0] = ((uint4*)tmp)[0];
            *(uint4*)&Xl[pid * 16 + 8] = ((uint4*)tmp)[1];
        }
        // W stage: 9 taps x 64 co x 16 ci = 1152 uint4
        {
            const uint4* wsrc = (const uint4*)wpack;
            const int base = ch * 2304 + (co0 << 1);
            for (int idx = t; idx < 1152; idx += 256)
                ((uint4*)Wl)[idx] = wsrc[base + ((idx >> 7) << 8) + (idx & 127)];
        }
        __syncthreads();

#pragma unroll 3
        for (int tap = 0; tap < 9; ++tap) {
            const int dy = tap / 3, dx = tap - dy * 3;
            short8 a = *(const short8*)&Wl[((tap << 6) + (wy << 5) + l31) * 16 + (g << 3)];
            const int row = wx + dy;
            short8 b0 = *(const short8*)&Xl[(row * 66 + l31 + dx) * 16 + (g << 3)];
            short8 b1 = *(const short8*)&Xl[(row * 66 + l31 + 32 + dx) * 16 + (g << 3)];
            acc0 = __builtin_amdgcn_mfma_f32_32x32x16_bf16(a, b0, acc0, 0, 0, 0);
            acc1 = __builtin_amdgcn_mfma_f32_32x32x16_bf16(a, b1, acc1, 0, 0, 0);
        }
        __syncthreads();
    }

    const int y = y0 + wx;
#pragma unroll
    for (int j = 0; j < 2; j++) {
        const f32x16 a = j ? acc1 : acc0;
#pragma unroll
        for (int r = 0; r < 16; r++) {
            int co = co0 + (wy << 5) + (r & 3) + ((r >> 2) << 3) + (g << 2);
            int x  = (j << 5) + l31;
            float v = fmaf(a[r], bn[co], bn[128 + co]);
            v = v > 0.f ? v : 0.f;
            size_t o = (((size_t)b * 128 + co) << 12) + (y << 6) + x;
            if (out_f32) out_f32[o] = v;
            if (out_bf)  out_bf[o]  = f2bf(v);
        }
    }
}

// ---- 3x3 conv, hi/lo split MFMA (~fp32), co-split. grid (32, 2, 8) --------
// Optional bf16 hi/lo activation outputs (for the CAM Gram).
__global__ __launch_bounds__(256) void conv3x3_mfma_hilo(
    const float* __restrict__ xin, int Cin,
    const unsigned short* __restrict__ wph, const unsigned short* __restrict__ wpl,
    const float* __restrict__ bn, float* __restrict__ out_f32,
    unsigned short* __restrict__ outh, unsigned short* __restrict__ outl)
{
    const int t   = threadIdx.x;
    const int w   = t >> 6;
    const int wy  = w >> 1;
    const int wx  = w & 1;
    const int ln  = t & 63;
    const int l31 = ln & 31;
    const int g   = ln >> 5;
    const int y0  = blockIdx.x << 1;
    const int co0 = blockIdx.y << 6;
    const int b   = blockIdx.z;

    __shared__ __align__(16) unsigned short Xh[4 * 66 * 16];
    __shared__ __align__(16) unsigned short Xo[4 * 66 * 16];
    __shared__ __align__(16) unsigned short Wh[9 * 64 * 16];
    __shared__ __align__(16) unsigned short Wo[9 * 64 * 16];

    const f32x16 zero = {0,0,0,0,0,0,0,0,0,0,0,0,0,0,0,0};
    f32x16 acc0 = zero, acc1 = zero;

    const int nchunks = Cin >> 4;
    for (int ch = 0; ch < nchunks; ++ch) {
        const int cin0 = ch << 4;
        for (int pid = t; pid < 264; pid += 256) {
            int r  = pid / 66;
            int xc = pid - r * 66;
            int gy = y0 - 1 + r;
            int gx = xc - 1;
            unsigned short th[16], tl[16];
            if ((unsigned)gy < 64u && (unsigned)gx < 64u) {
                const float* src = xin + (((size_t)b * Cin + cin0) << 12) + (gy << 6) + gx;
#pragma unroll
                for (int c = 0; c < 16; c++) {
                    float f = src[(size_t)c << 12];
                    unsigned short hi = f2bf(f);
                    th[c] = hi;
                    tl[c] = f2bf(f - bf2f(hi));
                }
            } else {
#pragma unroll
                for (int c = 0; c < 16; c++) { th[c] = 0; tl[c] = 0; }
            }
            *(uint4*)&Xh[pid * 16 + 0] = ((uint4*)th)[0];
            *(uint4*)&Xh[pid * 16 + 8] = ((uint4*)th)[1];
            *(uint4*)&Xo[pid * 16 + 0] = ((uint4*)tl)[0];
            *(uint4*)&Xo[pid * 16 + 8] = ((uint4*)tl)[1];
        }
        {
            const uint4* sh = (const uint4*)wph;
            const uint4* sl = (const uint4*)wpl;
            const int base = ch * 2304 + (co0 << 1);
            for (int idx = t; idx < 1152; idx += 256) {
                int o = base + ((idx >> 7) << 8) + (idx & 127);
                ((uint4*)Wh)[idx] = sh[o];
                ((uint4*)Wo)[idx] = sl[o];
            }
        }
        __syncthreads();

#pragma unroll 1
        for (int tap = 0; tap < 9; ++tap) {
            const int dy = tap / 3, dx = tap - dy * 3;
            const int wi = ((tap << 6) + (wy << 5) + l31) * 16 + (g << 3);
            const int row = wx + dy;
            const int xi0 = (row * 66 + l31 + dx) * 16 + (g << 3);
            const int xi1 = (row * 66 + l31 + 32 + dx) * 16 + (g << 3);
            short8 ah = *(const short8*)&Wh[wi];
            short8 al = *(const short8*)&Wo[wi];
            short8 b0h = *(const short8*)&Xh[xi0];
            short8 b1h = *(const short8*)&Xh[xi1];
            short8 b0l = *(const short8*)&Xo[xi0];
            short8 b1l = *(const short8*)&Xo[xi1];
            acc0 = __builtin_amdgcn_mfma_f32_32x32x16_bf16(ah, b0h, acc0, 0, 0, 0);
            acc1 = __builtin_amdgcn_mfma_f32_32x32x16_bf16(ah, b1h, acc1, 0, 0, 0);
            acc0 = __builtin_amdgcn_mfma_f32_32x32x16_bf16(ah, b0l, acc0, 0, 0, 0);
            acc1 = __builtin_amdgcn_mfma_f32_32x32x16_bf16(ah, b1l, acc1, 0, 0, 0);
            acc0 = __builtin_amdgcn_mfma_f32_32x32x16_bf16(al, b0h, acc0, 0, 0, 0);
            acc1 = __builtin_amdgcn_mfma_f32_32x32x16_bf16(al, b1h, acc1, 0, 0, 0);
        }
        __syncthreads();
    }

    const int y = y0 + wx;
#pragma unroll
    for (int j = 0; j < 2; j++) {
        const f32x16 a = j ? acc1 : acc0;
#pragma unroll
        for (int r = 0; r < 16; r++) {
            int co = co0 + (wy << 5) + (r & 3) + ((r >> 2) << 3) + (g << 2);
            int x  = (j << 5) + l31;
            float v = fmaf(a[r], bn[co], bn[128 + co]);
            v = v > 0.f ? v : 0.f;
            size_t o = (((size_t)b * 128 + co) << 12) + (y << 6) + x;
            out_f32[o] = v;
            if (outh) {
                unsigned short hi = f2bf(v);
                outh[o] = hi;
                outl[o] = f2bf(v - bf2f(hi));
            }
        }
    }
}

// ---- CAM Gram via hi/lo MFMA, n-split partials. grid (16, 8, 8) -----------
__global__ __launch_bounds__(256) void cam_energy_mfma(
    const unsigned short* __restrict__ bh, const unsigned short* __restrict__ bl,
    float* __restrict__ egy_part)
{
    const int t   = threadIdx.x;
    const int w   = t >> 6;
    const int ln  = t & 63;
    const int l31 = ln & 31;
    const int g   = ln >> 5;
    const int i0  = (blockIdx.x >> 2) << 5;
    const int j0  = (blockIdx.x & 3) << 5;
    const int nseg = blockIdx.y;
    const int b   = blockIdx.z;

    __shared__ float red[4][64][17];

    const f32x16 zero = {0,0,0,0,0,0,0,0,0,0,0,0,0,0,0,0};
    f32x16 acc = zero;
    const int nb = (nseg << 9) + (w << 7) + (g << 3);
    const size_t ri = ((size_t)b * 128 + i0 + l31) << 12;
    const size_t rj = ((size_t)b * 128 + j0 + l31) << 12;

#pragma unroll
    for (int c = 0; c < 8; c++) {
        const int n0 = nb + (c << 4);
        short8 ah  = *(const short8*)(bh + ri + n0);
        short8 al  = *(const short8*)(bl + ri + n0);
        short8 bhf = *(const short8*)(bh + rj + n0);
        short8 blf = *(const short8*)(bl + rj + n0);
        acc = __builtin_amdgcn_mfma_f32_32x32x16_bf16(ah, bhf, acc, 0, 0, 0);
        acc = __builtin_amdgcn_mfma_f32_32x32x16_bf16(ah, blf, acc, 0, 0, 0);
        acc = __builtin_amdgcn_mfma_f32_32x32x16_bf16(al, bhf, acc, 0, 0, 0);
    }
#pragma unroll
    for (int r = 0; r < 16; r++) red[w][ln][r] = acc[r];
    __syncthreads();

    const int lane = t & 63;
    const int rq   = t >> 6;
    float* base = egy_part + (((size_t)(nseg * 8 + b)) << 14);
#pragma unroll
    for (int e = 0; e < 4; e++) {
        const int reg = (rq << 2) + e;
        float v = red[0][lane][reg] + red[1][lane][reg]
                + red[2][lane][reg] + red[3][lane][reg];
        const int i = i0 + (reg & 3) + ((reg >> 2) << 3) + ((lane >> 5) << 2);
        base[i * 128 + j0 + (lane & 31)] = v;
    }
}

// ---- CAM softmax of (rowmax - e), fused 8-seg reduce. grid (8, 8) ---------
__global__ __launch_bounds__(256) void cam_softmax_fused(
    const float* __restrict__ egy_part, float* __restrict__ egy)
{
    const int b   = blockIdx.x;
    const int rg  = blockIdx.y;
    const int t   = threadIdx.x;
    const int row = (rg << 4) + (t >> 4);
    const int jg  = t & 15;

    float e[8];
#pragma unroll
    for (int jj = 0; jj < 8; jj++) e[jj] = 0.f;
    for (int seg = 0; seg < 8; seg++) {
        const float* p = egy_part + (((size_t)(seg * 8 + b)) << 14) + row * 128 + (jg << 3);
#pragma unroll
        for (int jj = 0; jj < 8; jj++) e[jj] += p[jj];
    }
    float mn = e[0];
#pragma unroll
    for (int jj = 1; jj < 8; jj++) mn = fminf(mn, e[jj]);
#pragma unroll
    for (int k = 1; k < 16; k <<= 1) mn = fminf(mn, __shfl_xor(mn, k));
    float s = 0.f;
#pragma unroll
    for (int jj = 0; jj < 8; jj++) { float p = __expf(mn - e[jj]); e[jj] = p; s += p; }
#pragma unroll
    for (int k = 1; k < 16; k <<= 1) s += __shfl_xor(s, k);
    const float inv = 1.f / s;
    float* orow = egy + ((size_t)b << 14) + row * 128 + (jg << 3);
#pragma unroll
    for (int jj = 0; jj < 8; jj++) orow[jj] = e[jj] * inv;
}

// ---- PAM Q/K producer ----
__global__ __launch_bounds__(256) void pam_qk_1x1(
    const float* __restrict__ A, const float* __restrict__ Wb, const float* __restrict__ bb,
    const float* __restrict__ Wc, const float* __restrict__ bc,
    unsigned short* __restrict__ qt, unsigned short* __restrict__ kt)
{
    __shared__ float wl[2 * 16 * 128];
    __shared__ float bl[32];
    const int t = threadIdx.x;
    const int n = (blockIdx.x << 8) + t;
    const int b = blockIdx.y;
    for (int idx = t; idx < 2048; idx += 256) { wl[idx] = Wb[idx]; wl[2048 + idx] = Wc[idx]; }
    if (t < 16) { bl[t] = bb[t]; bl[16 + t] = bc[t]; }
    __syncthreads();
    float ab[16], ac[16];
#pragma unroll
    for (int k = 0; k < 16; k++) { ab[k] = 0.f; ac[k] = 0.f; }
    for (int chn = 0; chn < 128; ++chn) {
        float a = A[(((size_t)b * 128 + chn) << 12) + n];
#pragma unroll
        for (int k = 0; k < 16; k++) {
            ab[k] = fmaf(wl[k * 128 + chn], a, ab[k]);
            ac[k] = fmaf(wl[2048 + k * 128 + chn], a, ac[k]);
        }
    }
    unsigned short uq[16], uk[16];
#pragma unroll
    for (int k = 0; k < 16; k++) {
        uq[k] = f2bf(ab[k] + bl[k]);
        uk[k] = f2bf(ac[k] + bl[16 + k]);
    }
    size_t row = (size_t)b * 4096 + n;
    ((uint4*)qt)[row * 2 + 0] = ((uint4*)uq)[0];
    ((uint4*)qt)[row * 2 + 1] = ((uint4*)uq)[1];
    ((uint4*)kt)[row * 2 + 0] = ((uint4*)uk)[0];
    ((uint4*)kt)[row * 2 + 1] = ((uint4*)uk)[1];
}

// ---- PAM V producer ----
__global__ __launch_bounds__(256) void pam_v_1x1(
    const float* __restrict__ A, const float* __restrict__ Wd, const float* __restrict__ bd,
    unsigned short* __restrict__ vb)
{
    __shared__ float wl[32 * 128];
    __shared__ float bl[32];
    const int t   = threadIdx.x;
    const int n   = (blockIdx.x << 8) + t;
    const int co0 = blockIdx.y << 5;
    const int b   = blockIdx.z;
    for (int idx = t; idx < 4096; idx += 256) {
        int c2 = idx >> 7, chv = idx & 127;
        wl[idx] = Wd[(co0 + c2) * 128 + chv];
    }
    if (t < 32) bl[t] = bd[co0 + t];
    __syncthreads();
    float acc[32];
#pragma unroll
    for (int k = 0; k < 32; k++) acc[k] = 0.f;
    for (int chn = 0; chn < 128; ++chn) {
        float a = A[(((size_t)b * 128 + chn) << 12) + n];
#pragma unroll
        for (int k = 0; k < 32; k++) acc[k] = fmaf(wl[k * 128 + chn], a, acc[k]);
    }
#pragma unroll
    for (int k = 0; k < 32; k++)
        vb[(((size_t)b * 128 + co0 + k) << 12) + n] = f2bf(acc[k] + bl[k]);
}

// ---- PAM rowmax ----
__global__ __launch_bounds__(256) void pam_rowmax(
    const unsigned short* __restrict__ qt, const unsigned short* __restrict__ kt,
    float* __restrict__ rowmax)
{
    const int t  = threadIdx.x;
    const int w  = t >> 6;
    const int L  = t & 63;
    const int ln = L & 31;
    const int g  = L >> 5;
    const int b  = blockIdx.y;
    const int n0 = blockIdx.x << 5;
    __shared__ float red[4][32];

    const f32x16 zero = {0,0,0,0,0,0,0,0,0,0,0,0,0,0,0,0};
    short8 qfrag = *(const short8*)(qt + (((size_t)b * 4096 + n0 + ln) << 4) + (g << 3));

    float mx = -INFINITY;
    for (int mq = (w << 5); mq < 4096; mq += 128) {
        short8 kfrag = *(const short8*)(kt + (((size_t)b * 4096 + mq + ln) << 4) + (g << 3));
        f32x16 s = __builtin_amdgcn_mfma_f32_32x32x16_bf16(kfrag, qfrag, zero, 0, 0, 0);
#pragma unroll
        for (int r = 0; r < 16; r++) mx = fmaxf(mx, s[r]);
    }
    mx = fmaxf(mx, __shfl_xor(mx, 32));
    if (L < 32) red[w][L] = mx;
    __syncthreads();
    if (t < 32) {
        float m = fmaxf(fmaxf(red[0][t], red[1][t]), fmaxf(red[2][t], red[3][t]));
        rowmax[((size_t)b << 12) + n0 + t] = m;
    }
}

// ---- PAM attention, MFMA; out = bf16 (feeds conv2p) -----------------------
__global__ __launch_bounds__(256) void pam_attn_mfma(
    const unsigned short* __restrict__ qt, const unsigned short* __restrict__ kt,
    const unsigned short* __restrict__ vb, const float* __restrict__ rowmax,
    const float* __restrict__ alpha, const float* __restrict__ Y,
    unsigned short* __restrict__ outb)
{
    const int t  = threadIdx.x;
    const int w  = t >> 6;
    const int L  = t & 63;
    const int ln = L & 31;
    const int g  = L >> 5;
    const int b  = blockIdx.y;
    const int n0 = blockIdx.x << 5;
    const int c0 = w << 5;

    __shared__ unsigned short Pf[16 * 256];
    __shared__ float red[4][32];

    const f32x16 zero = {0,0,0,0,0,0,0,0,0,0,0,0,0,0,0,0};
    short8 qfrag = *(const short8*)(qt + (((size_t)b * 4096 + n0 + ln) << 4) + (g << 3));
    const float rm = rowmax[((size_t)b << 12) + n0 + ln];
    const float al = alpha[0];

    f32x16 acc = zero;
    float rs = 0.f;

    for (int m0 = 0; m0 < 4096; m0 += 128) {
        const int mq = m0 + (w << 5);
        short8 kfrag = *(const short8*)(kt + (((size_t)b * 4096 + mq + ln) << 4) + (g << 3));
        f32x16 s = __builtin_amdgcn_mfma_f32_32x32x16_bf16(kfrag, qfrag, zero, 0, 0, 0);

        float p[16];
#pragma unroll
        for (int r = 0; r < 16; r++) { p[r] = __expf(s[r] - rm); rs += p[r]; }
        float xx[16];
#pragma unroll
        for (int r = 0; r < 16; r++) xx[r] = __shfl_xor(p[r], 32);

        unsigned short f0[8], f1[8];
#pragma unroll
        for (int i = 0; i < 4; i++) {
            f0[i]     = f2bf(g ? xx[4 + i]  : p[i]);
            f0[4 + i] = f2bf(g ? p[4 + i]   : xx[i]);
            f1[i]     = f2bf(g ? xx[12 + i] : p[8 + i]);
            f1[4 + i] = f2bf(g ? p[12 + i]  : xx[8 + i]);
        }
        *(short8*)(&Pf[((w << 2) + g) * 256 + (ln << 3)])     = *(short8*)f0;
        *(short8*)(&Pf[((w << 2) + 2 + g) * 256 + (ln << 3)]) = *(short8*)f1;
        __syncthreads();

#pragma unroll
        for (int kk = 0; kk < 8; kk++) {
            short8 pfrag = *(const short8*)(&Pf[((kk << 1) + g) * 256 + (ln << 3)]);
            short8 vfrag = *(const short8*)(vb + (((size_t)b * 128 + c0 + ln) << 12)
                                               + m0 + (kk << 4) + (g << 3));
            acc = __builtin_amdgcn_mfma_f32_32x32x16_bf16(vfrag, pfrag, acc, 0, 0, 0);
        }
        __syncthreads();
    }

    rs += __shfl_xor(rs, 32);
    if (L < 32) red[w][L] = rs;
    __syncthreads();
    const float inv = 1.f / (red[0][ln] + red[1][ln] + red[2][ln] + red[3][ln]);
    const int n = n0 + ln;
#pragma unroll
    for (int r = 0; r < 16; r++) {
        int c = c0 + (r & 3) + ((r >> 2) << 3) + (g << 2);
        size_t idx = (((size_t)b * 128 + c) << 12) + n;
        outb[idx] = f2bf(fmaf(al, acc[r] * inv, Y[idx]));
    }
}

// ---- CAM feat: fp32 out (feeds conv2c hilo) ----
__global__ __launch_bounds__(256) void cam_feat(
    const float* __restrict__ attn, const float* __restrict__ Bf,
    const float* __restrict__ beta, float* __restrict__ outf)
{
    const int t  = threadIdx.x;
    const int n  = (blockIdx.x << 8) + t;
    const int c0 = blockIdx.y << 5;
    const int b  = blockIdx.z;
    __shared__ float al[32 * 128];
    for (int idx = t; idx < 4096; idx += 256)
        al[idx] = attn[(size_t)b * 16384 + (c0 + (idx >> 7)) * 128 + (idx & 127)];
    __syncthreads();
    float acc[32];
#pragma unroll
    for (int k = 0; k < 32; k++) acc[k] = 0.f;
    for (int d = 0; d < 128; ++d) {
        float v = Bf[(((size_t)b * 128 + d) << 12) + n];
#pragma unroll
        for (int k = 0; k < 32; k++) acc[k] = fmaf(al[k * 128 + d], v, acc[k]);
    }
    float be = beta[0];
#pragma unroll
    for (int k = 0; k < 32; k++) {
        size_t idx = (((size_t)b * 128 + c0 + k) << 12) + n;
        outf[idx] = fmaf(be, acc[k], Bf[idx]);
    }
}

// ---- Final heads ----
__global__ __launch_bounds__(256) void heads(
    const float* __restrict__ FP, const float* __restrict__ FC,
    const float* __restrict__ Wout, const float* __restrict__ bout,
    const float* __restrict__ Wp3, const float* __restrict__ bp3,
    const float* __restrict__ Wc3, const float* __restrict__ bc3,
    float* __restrict__ out)
{
    const int t = threadIdx.x;
    const int n = (blockIdx.x << 8) + t;
    const int b = blockIdx.y;
    __shared__ float wl[3 * 19 * 128];
    __shared__ float bl[3 * 19];
    for (int idx = t; idx < 2432; idx += 256) {
        wl[idx]        = Wout[idx];
        wl[2432 + idx] = Wp3[idx];
        wl[4864 + idx] = Wc3[idx];
    }
    if (t < 19) { bl[t] = bout[t]; bl[19 + t] = bp3[t]; bl[38 + t] = bc3[t]; }
    __syncthreads();
    float am[19], ap[19], ac[19];
#pragma unroll
    for (int o = 0; o < 19; o++) { am[o] = 0.f; ap[o] = 0.f; ac[o] = 0.f; }
    for (int chn = 0; chn < 128; ++chn) {
        float pv = FP[(((size_t)b * 128 + chn) << 12) + n];
        float cv = FC[(((size_t)b * 128 + chn) << 12) + n];
        float fv = pv + cv;
#pragma unroll
        for (int o = 0; o < 19; o++) {
            am[o] = fmaf(wl[o * 128 + chn], fv, am[o]);
            ap[o] = fmaf(wl[2432 + o * 128 + chn], pv, ap[o]);
            ac[o] = fmaf(wl[4864 + o * 128 + chn], cv, ac[o]);
        }
    }
    const size_t OS = (size_t)8 * 19 * 4096;
#pragma unroll
    for (int o = 0; o < 19; o++) {
        size_t base = (((size_t)b * 19 + o) << 12) + n;
        out[base]          = 1.f / (1.f + __expf(-(am[o] + bl[o])));
        out[OS + base]     = 1.f / (1.f + __expf(-(ap[o] + bl[19 + o])));
        out[2 * OS + base] = 1.f / (1.f + __expf(-(ac[o] + bl[38 + o])));
    }
}

extern "C" void kernel_launch(void* const* d_in, const int* in_sizes, int n_in,
                              void* d_out, int out_size, void* d_ws, size_t ws_size,
                              hipStream_t stream)
{
    const float* x     = (const float*)d_in[0];
    const float* Wp1   = (const float*)d_in[1];
    const float* bnp1  = (const float*)d_in[2];
    const float* Wc1   = (const float*)d_in[3];
    const float* bnc1  = (const float*)d_in[4];
    const float* Wb    = (const float*)d_in[5];
    const float* bb    = (const float*)d_in[6];
    const float* Wc    = (const float*)d_in[7];
    const float* bcv   = (const float*)d_in[8];
    const float* Wd    = (const float*)d_in[9];
    const float* bd    = (const float*)d_in[10];
    const float* alpha = (const float*)d_in[11];
    const float* beta  = (const float*)d_in[12];
    const float* Wp2   = (const float*)d_in[13];
    const float* bnp2  = (const float*)d_in[14];
    const float* Wc2   = (const float*)d_in[15];
    const float* bnc2  = (const float*)d_in[16];
    const float* Wout  = (const float*)d_in[17];
    const float* bo    = (const float*)d_in[18];
    const float* Wp3   = (const float*)d_in[19];
    const float* bp3   = (const float*)d_in[20];
    const float* Wc3   = (const float*)d_in[21];
    const float* bc3   = (const float*)d_in[22];
    float* out = (float*)d_out;

    char* ws = (char*)d_ws;
    const size_t MB = 1u << 20;
    const size_t W1SZ = (size_t)32 * 18432 * 2;
    const size_t W2SZ = (size_t)8 * 18432 * 2;
    float*          bufA     = (float*)(ws);
    float*          bufB     = (float*)(ws + 16 * MB);
    unsigned short* vb       = (unsigned short*)(ws + 32 * MB);  // 8MB
    float*          egy_part = (float*)(ws + 40 * MB);           // 4MB
    float*          bufD     = (float*)(ws + 32 * MB);           // conv2p out (later)
    unsigned short* bh       = (unsigned short*)(ws + 48 * MB);  // 8MB
    unsigned short* blo      = (unsigned short*)(ws + 56 * MB);  // 8MB
    unsigned short* pam_bf   = (unsigned short*)(ws + 48 * MB);  // after Gram
    float*          camf     = (float*)(ws + 48 * MB);           // after conv2p
    unsigned short* qt       = (unsigned short*)(ws + 64 * MB);
    unsigned short* kt       = (unsigned short*)(ws + 65 * MB);
    float*          rowmax   = (float*)(ws + 66 * MB);
    float*          egy      = (float*)(ws + 66 * MB + (1u << 17));
    unsigned short* wp1      = (unsigned short*)(ws + 67 * MB);
    unsigned short* wc1h     = (unsigned short*)(ws + 67 * MB + W1SZ);
    unsigned short* wc1l     = (unsigned short*)(ws + 67 * MB + 2 * W1SZ);
    unsigned short* wp2      = (unsigned short*)(ws + 67 * MB + 3 * W1SZ);
    unsigned short* wc2h     = (unsigned short*)(ws + 67 * MB + 3 * W1SZ + W2SZ);
    unsigned short* wc2l     = (unsigned short*)(ws + 67 * MB + 3 * W1SZ + 2 * W2SZ);

    dim3 blk(256);
    const int n1 = 32 * 18432;
    const int n2 = 8 * 18432;
    wpack_kernel<<<dim3((n1 + 255) / 256), blk, 0, stream>>>(Wp1, wp1, 512, n1);
    wpack_kernel<<<dim3((n2 + 255) / 256), blk, 0, stream>>>(Wp2, wp2, 128, n2);
    wpack_split_kernel<<<dim3((n1 + 255) / 256), blk, 0, stream>>>(Wc1, wc1h, wc1l, 512, n1);
    wpack_split_kernel<<<dim3((n2 + 255) / 256), blk, 0, stream>>>(Wc2, wc2h, wc2l, 128, n2);

    // conv1p (plain) and conv1c (hilo, + bf16 hi/lo activations for the Gram)
    conv3x3_mfma<<<dim3(32, 2, 8), blk, 0, stream>>>(x, 1, 512, wp1, bnp1, bufA, (unsigned short*)0);
    conv3x3_mfma_hilo<<<dim3(32, 2, 8), blk, 0, stream>>>(x, 512, wc1h, wc1l, bnc1, bufB, bh, blo);
    // CAM Gram + softmax (consumes bh/bl, egy_part)
    cam_energy_mfma<<<dim3(16, 8, 8), blk, 0, stream>>>(bh, blo, egy_part);
    cam_softmax_fused<<<dim3(8, 8), blk, 0, stream>>>(egy_part, egy);
    // PAM
    pam_qk_1x1<<<dim3(16, 8), blk, 0, stream>>>(bufA, Wb, bb, Wc, bcv, qt, kt);
    pam_v_1x1<<<dim3(16, 4, 8), blk, 0, stream>>>(bufA, Wd, bd, vb);
    pam_rowmax<<<dim3(128, 8), blk, 0, stream>>>(qt, kt, rowmax);
    pam_attn_mfma<<<dim3(128, 8), blk, 0, stream>>>(qt, kt, vb, rowmax, alpha, bufA, pam_bf);
    // conv2p (reads pam_bf, writes bufD over vb/egy_part which are now dead)
    conv3x3_mfma<<<dim3(32, 2, 8), blk, 0, stream>>>(pam_bf, 0, 128, wp2, bnp2, bufD, (unsigned short*)0);
    // CAM tail (camf overwrites pam_bf after conv2p consumed it)
    cam_feat<<<dim3(16, 4, 8), blk, 0, stream>>>(egy, bufB, beta, camf);
    conv3x3_mfma_hilo<<<dim3(32, 2, 8), blk, 0, stream>>>(camf, 128, wc2h, wc2l, bnc2, bufA,
                                                          (unsigned short*)0, (unsigned short*)0);
    // fusion + heads
    heads<<<dim3(16, 8), blk, 0, stream>>>(bufD, bufA, Wout, bo, Wp3, bp3, Wc3, bc3, out);
}